// Round 2
// baseline (1023.460 us; speedup 1.0000x reference)
//
#include <hip/hip_runtime.h>
#include <math.h>

// Problem constants: b=4, c=256, heads=8, c/head=32, h=w=128, n=16384, cr=16
#define NFFT 16384
static constexpr size_t NP = 16777216; // one plane = 1024 * 16384 floats

// ---------- helpers ----------
__device__ __forceinline__ void sincos_rev(float rv, float& sn, float& cs){
    // v_sin/v_cos take input in revolutions: sin(2*pi*rv)
    sn = __builtin_amdgcn_sinf(rv);
    cs = __builtin_amdgcn_cosf(rv);
}
__device__ __forceinline__ int rev7(int v){ return (int)(__brev((unsigned)v) >> 25); }

// 128-pt FFT across one wave: lane l holds slot l (r0,i0) and slot l+64 (r1,i1).
// DIF forward: natural-order input, output slot j holds X[rev7(j)]. W = e^{-2pi i/128}
__device__ __forceinline__ void dif128(float& r0, float& i0, float& r1, float& i1){
    const int l = threadIdx.x & 63;
    {   // span 64 (between the two slots); twiddle W^l on difference
        float sn, cs; sincos_rev(-(float)l * 0.0078125f, sn, cs);
        float ar = r0 + r1, ai = i0 + i1;
        float br = r0 - r1, bi = i0 - i1;
        r0 = ar; i0 = ai;
        r1 = br*cs - bi*sn; i1 = br*sn + bi*cs;
    }
    #pragma unroll
    for (int m = 32; m >= 1; m >>= 1){
        int e = (l & (m-1)) * (64/m);
        float sn, cs; sincos_rev(-(float)e * 0.0078125f, sn, cs);
        bool up = (l & m) != 0;
        float pr = __shfl_xor(r0, m, 64), pi = __shfl_xor(i0, m, 64);
        float tr = up ? (pr - r0) : (r0 + pr);
        float ti = up ? (pi - i0) : (i0 + pi);
        r0 = up ? (tr*cs - ti*sn) : tr;
        i0 = up ? (tr*sn + ti*cs) : ti;
        pr = __shfl_xor(r1, m, 64); pi = __shfl_xor(i1, m, 64);
        tr = up ? (pr - r1) : (r1 + pr);
        ti = up ? (pi - i1) : (i1 + pi);
        r1 = up ? (tr*cs - ti*sn) : tr;
        i1 = up ? (tr*sn + ti*cs) : ti;
    }
}

// DIT inverse (unnormalized): input slot j holds X[rev7(j)], output natural order.
// W = e^{+2pi i/128}
__device__ __forceinline__ void dit128(float& r0, float& i0, float& r1, float& i1){
    const int l = threadIdx.x & 63;
    #pragma unroll
    for (int m = 1; m <= 32; m <<= 1){
        int e = (l & (m-1)) * (64/m);
        float sn, cs; sincos_rev((float)e * 0.0078125f, sn, cs);
        bool up = (l & m) != 0;
        float pr = __shfl_xor(r0, m, 64), pi = __shfl_xor(i0, m, 64);
        float vr = up ? r0 : pr, vi = up ? i0 : pi;       // value multiplied by w
        float wr = vr*cs - vi*sn, wi = vr*sn + vi*cs;
        r0 = up ? (pr - wr) : (r0 + wr);
        i0 = up ? (pi - wi) : (i0 + wi);
        pr = __shfl_xor(r1, m, 64); pi = __shfl_xor(i1, m, 64);
        vr = up ? r1 : pr; vi = up ? i1 : pi;
        wr = vr*cs - vi*sn; wi = vr*sn + vi*cs;
        r1 = up ? (pr - wr) : (r1 + wr);
        i1 = up ? (pi - wi) : (i1 + wi);
    }
    {   // span 64: w = e^{+2pi i l/128}
        float sn, cs; sincos_rev((float)l * 0.0078125f, sn, cs);
        float wr = r1*cs - i1*sn, wi = r1*sn + i1*cs;
        float ar = r0 + wr, ai = i0 + wi;
        r1 = r0 - wr; i1 = i0 - wi;
        r0 = ar; i0 = ai;
    }
}

// ---------- K1: fused forward fft2 per image. x[img] -> spectrum A,B; norm2[img].
// Output layout: P[img][j_w*128 + j_h] = FFT2[kh=rev7(j_h)][kw=rev7(j_w)]
__global__ __launch_bounds__(512) void k_fft2_fwd(const float* __restrict__ x,
                                                  float* __restrict__ ore, float* __restrict__ oim,
                                                  float* __restrict__ norm2){
    __shared__ float sr[128*129], si[128*129];
    __shared__ float red[8];
    int lane = threadIdx.x & 63, wave = threadIdx.x >> 6;   // 8 waves
    int img = blockIdx.x;
    const float* base = x + (size_t)img * NFFT;
    // phase 1: row FFTs (over w); store transposed S[j_w][h]
    #pragma unroll 1
    for (int it = 0; it < 16; ++it){
        int h = (wave << 4) + it;
        float a0 = base[h*128 + lane], b0 = 0.f;
        float a1 = base[h*128 + lane + 64], b1 = 0.f;
        dif128(a0, b0, a1, b1);
        sr[lane*129 + h] = a0;        si[lane*129 + h] = b0;
        sr[(lane+64)*129 + h] = a1;   si[(lane+64)*129 + h] = b1;
    }
    __syncthreads();
    // phase 2: col FFTs (over h, natural) per line j_w; write spectrum; accumulate |X|^2
    float acc = 0.f;
    #pragma unroll 1
    for (int it = 0; it < 16; ++it){
        int j = (wave << 4) + it;
        float a0 = sr[j*129 + lane],      b0 = si[j*129 + lane];
        float a1 = sr[j*129 + lane + 64], b1 = si[j*129 + lane + 64];
        dif128(a0, b0, a1, b1);
        size_t o = (size_t)img*NFFT + (size_t)j*128;
        ore[o + lane] = a0;      oim[o + lane] = b0;
        ore[o + lane + 64] = a1; oim[o + lane + 64] = b1;
        acc += a0*a0 + b0*b0 + a1*a1 + b1*b1;
    }
    #pragma unroll
    for (int m = 32; m >= 1; m >>= 1) acc += __shfl_xor(acc, m, 64);
    if (lane == 0) red[wave] = acc;
    __syncthreads();
    if (threadIdx.x == 0){
        float s = 0.f;
        #pragma unroll
        for (int i = 0; i < 8; ++i) s += red[i];
        norm2[img] = s;
    }
}

// ---------- K2: gram  G[bh][c][d] = sum_n X[c,n]*X[d,n]  (complex, NO conjugate) ----------
__global__ __launch_bounds__(256) void k_gram(const float* __restrict__ xre, const float* __restrict__ xim,
                                              float* __restrict__ G){
    __shared__ float lr[64*33], li[64*33];     // [n_local][ch]
    int t = threadIdx.x, lane = t & 63, wave = t >> 6;
    int bh = blockIdx.x >> 4;
    int n0 = (blockIdx.x & 15) << 10;          // 1024-wide n chunk
    size_t cbase = (size_t)bh * 32 * NFFT;
    int c0 = (lane >> 3) << 2, d0 = (lane & 7) << 2;
    float are[16], aim[16];
    #pragma unroll
    for (int i = 0; i < 16; ++i){ are[i] = 0.f; aim[i] = 0.f; }
    for (int nt = 0; nt < 16; ++nt){
        int nb = n0 + (nt << 6);
        __syncthreads();
        #pragma unroll
        for (int r = 0; r < 8; ++r){
            int ch = (wave << 3) + r;
            lr[lane*33 + ch] = xre[cbase + (size_t)ch*NFFT + nb + lane];
            li[lane*33 + ch] = xim[cbase + (size_t)ch*NFFT + nb + lane];
        }
        __syncthreads();
        for (int j = (wave<<4); j < (wave<<4) + 16; ++j){
            float xr[4], xi_[4], yr[4], yi[4];
            #pragma unroll
            for (int i = 0; i < 4; ++i){
                xr[i] = lr[j*33 + c0 + i]; xi_[i] = li[j*33 + c0 + i];
                yr[i] = lr[j*33 + d0 + i]; yi[i] = li[j*33 + d0 + i];
            }
            #pragma unroll
            for (int ci = 0; ci < 4; ++ci)
                #pragma unroll
                for (int di = 0; di < 4; ++di){
                    are[ci*4+di] += xr[ci]*yr[di] - xi_[ci]*yi[di];
                    aim[ci*4+di] += xr[ci]*yi[di] + xi_[ci]*yr[di];
                }
        }
    }
    float* gb = G + (size_t)bh * 2048;
    #pragma unroll
    for (int ci = 0; ci < 4; ++ci)
        for (int di = 0; di < 4; ++di){
            int idx = ((c0+ci)*32 + d0+di) * 2;
            atomicAdd(gb + idx,     are[ci*4+di]);
            atomicAdd(gb + idx + 1, aim[ci*4+di]);
        }
}

// ---------- K3: normalize, temperature, complex softmax, fold IF32 * (1/524288) ----------
__global__ __launch_bounds__(256) void k_attn(const float* __restrict__ G, const float* __restrict__ norm2,
                                              const float* __restrict__ temp, float* __restrict__ attn2){
    __shared__ float ar[32*33], ai[32*33];
    int bh = blockIdx.x, h = bh & 7, t = threadIdx.x;
    if (t < 32){
        float tv = temp[h];
        float nc = fmaxf(sqrtf(norm2[(bh<<5) + t]), 1e-12f);
        const float* gr = G + (size_t)bh*2048 + t*64;
        float mr = -1e30f, mi = -1e30f;
        for (int d = 0; d < 32; ++d){
            float nd = fmaxf(sqrtf(norm2[(bh<<5) + d]), 1e-12f);
            float s = tv / (nc * nd);
            float vr = gr[d*2] * s, vi = gr[d*2+1] * s;
            ar[t*33+d] = vr; ai[t*33+d] = vi;
            mr = fmaxf(mr, vr); mi = fmaxf(mi, vi);
        }
        float sr = 0.f, si = 0.f;
        for (int d = 0; d < 32; ++d){
            float er = __expf(ar[t*33+d] - mr), ei = __expf(ai[t*33+d] - mi);
            ar[t*33+d] = er; ai[t*33+d] = ei; sr += er; si += ei;
        }
        sr = 1.f/sr; si = 1.f/si;
        for (int d = 0; d < 32; ++d){ ar[t*33+d] *= sr; ai[t*33+d] *= si; }
    }
    __syncthreads();
    const float S = 1.f / 524288.f;  // (1/32 ifft over c') * (1/16384 ifft over n)
    for (int q = t; q < 1024; q += 256){
        int e = q >> 5, d = q & 31;
        float sr = 0.f, si = 0.f;
        for (int c = 0; c < 32; ++c){
            float sn, cs; sincos_rev((float)((e*c) & 31) * 0.03125f, sn, cs); // +2pi ec/32
            float xr = ar[c*33+d], xi = ai[c*33+d];
            sr += cs*xr - sn*xi;
            si += cs*xi + sn*xr;
        }
        attn2[(size_t)bh*2048 + q*2]     = sr * S;
        attn2[(size_t)bh*2048 + q*2 + 1] = si * S;
    }
}

// ---------- K4: mix[e][n] = sum_d attn2[e][d] * X[d][n]  (complex) ----------
__global__ __launch_bounds__(256) void k_mix(const float* __restrict__ xre, const float* __restrict__ xim,
                                             const float* __restrict__ attn2,
                                             float* __restrict__ ore, float* __restrict__ oim){
    __shared__ float a2[2048];
    __shared__ float lr[32*65], li[32*65];     // [ch][n_local]
    int t = threadIdx.x, lane = t & 63, wave = t >> 6;
    int bh = blockIdx.x >> 5;
    int n0 = (blockIdx.x & 31) << 9;           // 512-wide chunk
    size_t cbase = (size_t)bh * 32 * NFFT;
    {
        const float4* s4 = (const float4*)(attn2 + (size_t)bh*2048);
        float4* d4 = (float4*)a2;
        d4[t] = s4[t]; d4[t + 256] = s4[t + 256];
    }
    for (int tile = 0; tile < 8; ++tile){
        int nb = n0 + (tile << 6);
        __syncthreads();
        #pragma unroll
        for (int r = 0; r < 8; ++r){
            int ch = (wave << 3) + r;
            lr[ch*65 + lane] = xre[cbase + (size_t)ch*NFFT + nb + lane];
            li[ch*65 + lane] = xim[cbase + (size_t)ch*NFFT + nb + lane];
        }
        __syncthreads();
        float accr[8] = {0,0,0,0,0,0,0,0}, acci[8] = {0,0,0,0,0,0,0,0};
        for (int d = 0; d < 32; d += 2){
            float xr0 = lr[d*65 + lane],     xi0 = li[d*65 + lane];
            float xr1 = lr[(d+1)*65 + lane], xi1 = li[(d+1)*65 + lane];
            #pragma unroll
            for (int k = 0; k < 8; ++k){
                int e = (wave << 3) + k;
                const float4 w = *(const float4*)&a2[(e << 6) + (d << 1)];
                accr[k] += w.x*xr0 - w.y*xi0 + w.z*xr1 - w.w*xi1;
                acci[k] += w.x*xi0 + w.y*xr0 + w.z*xi1 + w.w*xr1;
            }
        }
        #pragma unroll
        for (int k = 0; k < 8; ++k){
            int e = (wave << 3) + k;
            ore[cbase + (size_t)e*NFFT + nb + lane] = accr[k];
            oim[cbase + (size_t)e*NFFT + nb + lane] = acci[k];
        }
    }
}

// ---------- K5: fused 16384-pt inverse FFT (four-step) + abs, per (b,head,e) row.
// In: (ire, io) complex row in [j_w*128+j_h] layout. Out: |y|[p_h*128+p_w] written into io. ----------
__global__ __launch_bounds__(512) void k_ifft_n(const float* ire, float* io){
    __shared__ float sr[128*129], si[128*129];
    int lane = threadIdx.x & 63, wave = threadIdx.x >> 6;
    size_t rb = (size_t)blockIdx.x * NFFT;
    // step A: per line j_w: DIT over kh -> p_w natural; twiddle e^{+2pi p_w kw/16384}; store S[p_w][j_w]
    #pragma unroll 1
    for (int it = 0; it < 16; ++it){
        int jw = (wave << 4) + it;
        size_t base = rb + ((size_t)jw << 7);
        float a0 = ire[base + lane], b0 = io[base + lane];
        float a1 = ire[base + lane + 64], b1 = io[base + lane + 64];
        dit128(a0, b0, a1, b1);
        int kw = rev7(jw);
        float sn, cs;
        sincos_rev((float)(lane * kw) * 6.103515625e-05f, sn, cs);
        float r = a0*cs - b0*sn, i2 = a0*sn + b0*cs;
        sr[lane*129 + jw] = r; si[lane*129 + jw] = i2;
        sincos_rev((float)((lane + 64) * kw) * 6.103515625e-05f, sn, cs);
        r = a1*cs - b1*sn; i2 = a1*sn + b1*cs;
        sr[(lane+64)*129 + jw] = r; si[(lane+64)*129 + jw] = i2;
    }
    __syncthreads();
    // step B: per line p_w: DIT over kw -> p_h natural; abs into registers
    float av[16][2];
    #pragma unroll 1
    for (int it = 0; it < 16; ++it){
        int pw = (wave << 4) + it;
        float a0 = sr[pw*129 + lane],      b0 = si[pw*129 + lane];
        float a1 = sr[pw*129 + lane + 64], b1 = si[pw*129 + lane + 64];
        dit128(a0, b0, a1, b1);
        av[it][0] = sqrtf(a0*a0 + b0*b0);
        av[it][1] = sqrtf(a1*a1 + b1*b1);
    }
    __syncthreads();
    // transpose abs -> A[p_h][p_w]
    #pragma unroll 1
    for (int it = 0; it < 16; ++it){
        int pw = (wave << 4) + it;
        sr[lane*129 + pw] = av[it][0];
        sr[(lane+64)*129 + pw] = av[it][1];
    }
    __syncthreads();
    int row = threadIdx.x >> 2, cb = (threadIdx.x & 3) << 5;
    size_t ob = rb + ((size_t)row << 7) + cb;
    const float* s = &sr[row*129 + cb];
    #pragma unroll
    for (int q = 0; q < 8; ++q)
        *(float4*)(io + ob + (q << 2)) = make_float4(s[q*4], s[q*4+1], s[q*4+2], s[q*4+3]);
}

// ---------- K6: gating, IN-PLACE: X *= sigmoid(w2@relu(BN(w1@Re(X)+b1))+b2) / 16384 ----------
__global__ __launch_bounds__(256) void k_gate(float* xre, float* xim,
                                              const float* __restrict__ w1, const float* __restrict__ b1,
                                              const float* __restrict__ bg, const float* __restrict__ bb_,
                                              const float* __restrict__ bm, const float* __restrict__ bv,
                                              const float* __restrict__ w2, const float* __restrict__ b2){
    __shared__ float w1T[256*16];     // [c][r]
    __shared__ float w2s[256*16];     // [o][r]
    int t = threadIdx.x;
    #pragma unroll
    for (int i = 0; i < 16; ++i) w1T[t*16 + i] = w1[i*256 + t];
    {
        const float4* s4 = (const float4*)w2; float4* d4 = (float4*)w2s;
        #pragma unroll
        for (int i = 0; i < 4; ++i) d4[i*256 + t] = s4[i*256 + t];
    }
    __syncthreads();
    int b = blockIdx.x >> 6;
    int n = ((blockIdx.x & 63) << 8) + t;
    size_t base = ((size_t)b << 8) * NFFT + n;
    float y[16];
    #pragma unroll
    for (int r = 0; r < 16; ++r) y[r] = 0.f;
    #pragma unroll 4
    for (int c = 0; c < 256; ++c){
        float xr = xre[base + (size_t)c*NFFT];
        #pragma unroll
        for (int r = 0; r < 16; ++r) y[r] += w1T[c*16 + r] * xr;
    }
    #pragma unroll
    for (int r = 0; r < 16; ++r){
        float v = y[r] + b1[r];
        v = (v - bm[r]) * rsqrtf(bv[r] + 1e-5f) * bg[r] + bb_[r];
        y[r] = fmaxf(v, 0.f);
    }
    #pragma unroll 2
    for (int o = 0; o < 256; ++o){
        float s = b2[o];
        #pragma unroll
        for (int r = 0; r < 16; ++r) s += w2s[o*16 + r] * y[r];
        float g = 1.f / (1.f + __expf(-s)) * 6.103515625e-05f;   // sigmoid * 1/16384
        float xr = xre[base + (size_t)o*NFFT];
        float xi = xim[base + (size_t)o*NFFT];
        xre[base + (size_t)o*NFFT] = g * xr;
        xim[base + (size_t)o*NFFT] = g * xi;
    }
}

// ---------- K7: fused ifft2 per image + abs. (re,im) in spectrum layout -> |y| into re plane ----------
__global__ __launch_bounds__(512) void k_ifft2_gate(float* re_io, const float* im_){
    __shared__ float sr[128*129], si[128*129];
    int lane = threadIdx.x & 63, wave = threadIdx.x >> 6;
    size_t ib = (size_t)blockIdx.x * NFFT;
    // phase 1: per line j_w: DIT over kh -> p_h natural; store S[p_h][j_w]
    #pragma unroll 1
    for (int it = 0; it < 16; ++it){
        int jw = (wave << 4) + it;
        size_t base = ib + ((size_t)jw << 7);
        float a0 = re_io[base + lane], b0 = im_[base + lane];
        float a1 = re_io[base + lane + 64], b1 = im_[base + lane + 64];
        dit128(a0, b0, a1, b1);
        sr[lane*129 + jw] = a0;        si[lane*129 + jw] = b0;
        sr[(lane+64)*129 + jw] = a1;   si[(lane+64)*129 + jw] = b1;
    }
    __syncthreads();
    // phase 2: per line p_h: DIT over kw -> p_w natural; abs; coalesced natural write
    #pragma unroll 1
    for (int it = 0; it < 16; ++it){
        int ph = (wave << 4) + it;
        float a0 = sr[ph*129 + lane],      b0 = si[ph*129 + lane];
        float a1 = sr[ph*129 + lane + 64], b1 = si[ph*129 + lane + 64];
        dit128(a0, b0, a1, b1);
        size_t o = ib + ((size_t)ph << 7);
        re_io[o + lane]      = sqrtf(a0*a0 + b0*b0);
        re_io[o + lane + 64] = sqrtf(a1*a1 + b1*b1);
    }
}

// ---------- K8: projection  out[b][o][n] = sum_{q<512} pw[o][q] * cat[b][q][n] ----------
__global__ __launch_bounds__(256) void k_proj(const float* __restrict__ cat0, const float* __restrict__ cat1,
                                              const float* __restrict__ pw, float* __restrict__ out){
    __shared__ float As[16*132];   // [kk][o]
    __shared__ float Bs[16*132];   // [kk][n]
    int t = threadIdx.x;
    int ot = blockIdx.x & 1;
    int nt = (blockIdx.x >> 1) & 127;
    int b  = blockIdx.x >> 8;
    int o0 = ot << 7, n0 = nt << 7;
    int to = t >> 4, tn = t & 15;
    float acc[8][8];
    #pragma unroll
    for (int i = 0; i < 8; ++i)
        #pragma unroll
        for (int j = 0; j < 8; ++j) acc[i][j] = 0.f;

    for (int kc = 0; kc < 32; ++kc){
        int kb = kc << 4;
        __syncthreads();
        {   // load A: 128 o x 16 k
            int o_l = t >> 1, kh8 = (t & 1) * 8;
            float4 a0 = *(const float4*)(pw + (size_t)(o0 + o_l)*512 + kb + kh8);
            float4 a1 = *(const float4*)(pw + (size_t)(o0 + o_l)*512 + kb + kh8 + 4);
            As[(kh8+0)*132 + o_l] = a0.x; As[(kh8+1)*132 + o_l] = a0.y;
            As[(kh8+2)*132 + o_l] = a0.z; As[(kh8+3)*132 + o_l] = a0.w;
            As[(kh8+4)*132 + o_l] = a1.x; As[(kh8+5)*132 + o_l] = a1.y;
            As[(kh8+6)*132 + o_l] = a1.z; As[(kh8+7)*132 + o_l] = a1.w;
        }
        {   // load B: 16 q x 128 n
            int q_l = t >> 4, nn = (t & 15) * 8;
            int q = kb + q_l;
            const float* srow = (q < 256) ? (cat0 + (size_t)((b<<8) + q) * NFFT)
                                          : (cat1 + (size_t)((b<<8) + q - 256) * NFFT);
            float4 v0 = *(const float4*)(srow + n0 + nn);
            float4 v1 = *(const float4*)(srow + n0 + nn + 4);
            *(float4*)&Bs[q_l*132 + nn]     = v0;
            *(float4*)&Bs[q_l*132 + nn + 4] = v1;
        }
        __syncthreads();
        #pragma unroll
        for (int kk = 0; kk < 16; ++kk){
            const float* ap = &As[kk*132 + (to<<3)];
            const float* bp = &Bs[kk*132 + (tn<<3)];
            float a[8], bvv[8];
            #pragma unroll
            for (int i = 0; i < 8; ++i){ a[i] = ap[i]; bvv[i] = bp[i]; }
            #pragma unroll
            for (int i = 0; i < 8; ++i)
                #pragma unroll
                for (int j = 0; j < 8; ++j) acc[i][j] += a[i] * bvv[j];
        }
    }
    #pragma unroll
    for (int i = 0; i < 8; ++i){
        float* orow = out + (size_t)((b<<8) + o0 + (to<<3) + i)*NFFT + n0 + (tn<<3);
        *(float4*)orow       = make_float4(acc[i][0], acc[i][1], acc[i][2], acc[i][3]);
        *(float4*)(orow + 4) = make_float4(acc[i][4], acc[i][5], acc[i][6], acc[i][7]);
    }
}

// ---------- host ----------
extern "C" void kernel_launch(void* const* d_in, const int* in_sizes, int n_in,
                              void* d_out, int out_size, void* d_ws, size_t ws_size,
                              hipStream_t stream) {
    const float* x    = (const float*)d_in[0];
    const float* temp = (const float*)d_in[1];
    const float* w1   = (const float*)d_in[2];
    const float* b1   = (const float*)d_in[3];
    const float* bg   = (const float*)d_in[4];
    const float* bb_  = (const float*)d_in[5];
    const float* bm   = (const float*)d_in[6];
    const float* bv   = (const float*)d_in[7];
    const float* w2   = (const float*)d_in[8];
    const float* b2   = (const float*)d_in[9];
    const float* pw   = (const float*)d_in[10];
    float* out = (float*)d_out;

    float* ws = (float*)d_ws;
    float* Are  = ws;            // spectrum re -> (gated, in-place) -> cat1
    float* Aim  = ws + NP;       // spectrum im
    float* Ecat = ws + 2*NP;     // mix im -> cat0 (in-place)
    float* norm2 = ws + 3*NP;                  // 1024
    float* G     = norm2 + 1024;               // 65536
    float* attn2 = G + 65536;                  // 65536
    float* mixre = out;                        // d_out doubles as mix-re scratch

    size_t need = (3*NP + 1024 + 65536 + 65536) * sizeof(float);
    if (ws_size < need) return;   // clean diagnostic failure instead of a fault

    hipMemsetAsync(G, 0, 65536 * sizeof(float), stream);

    // forward fft2: x -> spectrum (Are,Aim), per-channel norms
    k_fft2_fwd<<<1024, 512, 0, stream>>>(x, Are, Aim, norm2);
    // attention matrix
    k_gram<<<512, 256, 0, stream>>>(Are, Aim, G);
    k_attn<<<32, 256, 0, stream>>>(G, norm2, temp, attn2);
    // channel mix (attn applied + ifft over c' folded): -> (mixre=d_out, Ecat)
    k_mix<<<1024, 256, 0, stream>>>(Are, Aim, attn2, mixre, Ecat);
    // 16384-pt ifft + abs per row: (mixre, Ecat) -> cat0 in Ecat
    k_ifft_n<<<1024, 512, 0, stream>>>(mixre, Ecat);
    // gating branch in-place on spectrum, then ifft2 + abs -> cat1 in Are
    k_gate<<<256, 256, 0, stream>>>(Are, Aim, w1, b1, bg, bb_, bm, bv, w2, b2);
    k_ifft2_gate<<<1024, 512, 0, stream>>>(Are, Aim);
    // final projection: (cat0=Ecat, cat1=Are) -> out
    k_proj<<<1024, 256, 0, stream>>>(Ecat, Are, pw, out);
    (void)in_sizes; (void)n_in; (void)out_size; (void)ws_size;
}

// Round 4
// 944.989 us; speedup vs baseline: 1.0830x; 1.0830x over previous
//
#include <hip/hip_runtime.h>
#include <math.h>

// Problem constants: b=4, c=256, heads=8, c/head=32, h=w=128, n=16384, cr=16
#define NFFT 16384
static constexpr size_t NP = 16777216; // one plane = 1024 * 16384 floats

typedef short bf16x8 __attribute__((ext_vector_type(8)));
typedef float f32x4  __attribute__((ext_vector_type(4)));

// ---------- helpers ----------
__device__ __forceinline__ void sincos_rev(float rv, float& sn, float& cs){
    sn = __builtin_amdgcn_sinf(rv);   // sin(2*pi*rv)
    cs = __builtin_amdgcn_cosf(rv);
}
__device__ __forceinline__ int rev7(int v){ return (int)(__brev((unsigned)v) >> 25); }

// Per-lane FFT twiddles, hoisted: tw[lg] for stage m=2^lg (lg=0..5), tw[6] for the span-64 stage.
struct Tw { float c[7], s[7]; };
__device__ __forceinline__ void make_tw(Tw& t){
    const int l = threadIdx.x & 63;
    #pragma unroll
    for (int lg = 0; lg < 6; ++lg){
        int m = 1 << lg;
        int e = (l & (m-1)) * (64 >> lg);
        sincos_rev((float)e * 0.0078125f, t.s[lg], t.c[lg]);
    }
    sincos_rev((float)l * 0.0078125f, t.s[6], t.c[6]);
}

// DIF forward: natural in, slot j holds X[rev7(j)] out. W = e^{-2pi i/128}
__device__ __forceinline__ void dif128t(const Tw& t, float& r0, float& i0, float& r1, float& i1){
    const int l = threadIdx.x & 63;
    {   float cs = t.c[6], sn = -t.s[6];
        float ar = r0 + r1, ai = i0 + i1;
        float br = r0 - r1, bi = i0 - i1;
        r0 = ar; i0 = ai;
        r1 = br*cs - bi*sn; i1 = br*sn + bi*cs;
    }
    #pragma unroll
    for (int lg = 5; lg >= 0; --lg){
        int m = 1 << lg;
        float cs = t.c[lg], sn = -t.s[lg];
        bool up = (l & m) != 0;
        float pr = __shfl_xor(r0, m, 64), pi = __shfl_xor(i0, m, 64);
        float tr = up ? (pr - r0) : (r0 + pr);
        float ti = up ? (pi - i0) : (i0 + pi);
        r0 = up ? (tr*cs - ti*sn) : tr;
        i0 = up ? (tr*sn + ti*cs) : ti;
        pr = __shfl_xor(r1, m, 64); pi = __shfl_xor(i1, m, 64);
        tr = up ? (pr - r1) : (r1 + pr);
        ti = up ? (pi - i1) : (i1 + pi);
        r1 = up ? (tr*cs - ti*sn) : tr;
        i1 = up ? (tr*sn + ti*cs) : ti;
    }
}

// DIT inverse (unnormalized): slot j holds X[rev7(j)] in, natural out. W = e^{+2pi i/128}
__device__ __forceinline__ void dit128t(const Tw& t, float& r0, float& i0, float& r1, float& i1){
    const int l = threadIdx.x & 63;
    #pragma unroll
    for (int lg = 0; lg <= 5; ++lg){
        int m = 1 << lg;
        float cs = t.c[lg], sn = t.s[lg];
        bool up = (l & m) != 0;
        float pr = __shfl_xor(r0, m, 64), pi = __shfl_xor(i0, m, 64);
        float vr = up ? r0 : pr, vi = up ? i0 : pi;
        float wr = vr*cs - vi*sn, wi = vr*sn + vi*cs;
        r0 = up ? (pr - wr) : (r0 + wr);
        i0 = up ? (pi - wi) : (i0 + wi);
        pr = __shfl_xor(r1, m, 64); pi = __shfl_xor(i1, m, 64);
        vr = up ? r1 : pr; vi = up ? i1 : pi;
        wr = vr*cs - vi*sn; wi = vr*sn + vi*cs;
        r1 = up ? (pr - wr) : (r1 + wr);
        i1 = up ? (pi - wi) : (i1 + wi);
    }
    {   float cs = t.c[6], sn = t.s[6];
        float wr = r1*cs - i1*sn, wi = r1*sn + i1*cs;
        float ar = r0 + wr, ai = i0 + wi;
        r1 = r0 - wr; i1 = i0 - wi;
        r0 = ar; i0 = ai;
    }
}

// ---------- K1: fused forward fft2 per image. x[img] -> spectrum; norm2[img].
__global__ __launch_bounds__(512) void k_fft2_fwd(const float* __restrict__ x,
                                                  float* __restrict__ ore, float* __restrict__ oim,
                                                  float* __restrict__ norm2){
    __shared__ float sr[128*129], si[128*129];
    __shared__ float red[8];
    int lane = threadIdx.x & 63, wave = threadIdx.x >> 6;
    int img = blockIdx.x;
    Tw tw; make_tw(tw);
    const float* base = x + (size_t)img * NFFT;
    #pragma unroll 1
    for (int it = 0; it < 16; ++it){
        int h = (wave << 4) + it;
        float a0 = base[h*128 + lane], b0 = 0.f;
        float a1 = base[h*128 + lane + 64], b1 = 0.f;
        dif128t(tw, a0, b0, a1, b1);
        sr[lane*129 + h] = a0;        si[lane*129 + h] = b0;
        sr[(lane+64)*129 + h] = a1;   si[(lane+64)*129 + h] = b1;
    }
    __syncthreads();
    float acc = 0.f;
    #pragma unroll 1
    for (int it = 0; it < 16; ++it){
        int j = (wave << 4) + it;
        float a0 = sr[j*129 + lane],      b0 = si[j*129 + lane];
        float a1 = sr[j*129 + lane + 64], b1 = si[j*129 + lane + 64];
        dif128t(tw, a0, b0, a1, b1);
        size_t o = (size_t)img*NFFT + (size_t)j*128;
        ore[o + lane] = a0;      oim[o + lane] = b0;
        ore[o + lane + 64] = a1; oim[o + lane + 64] = b1;
        acc += a0*a0 + b0*b0 + a1*a1 + b1*b1;
    }
    #pragma unroll
    for (int m = 32; m >= 1; m >>= 1) acc += __shfl_xor(acc, m, 64);
    if (lane == 0) red[wave] = acc;
    __syncthreads();
    if (threadIdx.x == 0){
        float s = 0.f;
        #pragma unroll
        for (int i = 0; i < 8; ++i) s += red[i];
        norm2[img] = s;
    }
}

// ---------- K2: gram  G[bh][c][d] = sum_n X[c,n]*X[d,n]  (complex, NO conjugate) ----------
__global__ __launch_bounds__(256) void k_gram(const float* __restrict__ xre, const float* __restrict__ xim,
                                              float* __restrict__ G){
    __shared__ float lr[64*33], li[64*33];
    int t = threadIdx.x, lane = t & 63, wave = t >> 6;
    int bh = blockIdx.x >> 4;
    int n0 = (blockIdx.x & 15) << 10;
    size_t cbase = (size_t)bh * 32 * NFFT;
    int c0 = (lane >> 3) << 2, d0 = (lane & 7) << 2;
    float are[16], aim[16];
    #pragma unroll
    for (int i = 0; i < 16; ++i){ are[i] = 0.f; aim[i] = 0.f; }
    for (int nt = 0; nt < 16; ++nt){
        int nb = n0 + (nt << 6);
        __syncthreads();
        #pragma unroll
        for (int r = 0; r < 8; ++r){
            int ch = (wave << 3) + r;
            lr[lane*33 + ch] = xre[cbase + (size_t)ch*NFFT + nb + lane];
            li[lane*33 + ch] = xim[cbase + (size_t)ch*NFFT + nb + lane];
        }
        __syncthreads();
        for (int j = (wave<<4); j < (wave<<4) + 16; ++j){
            float xr[4], xi_[4], yr[4], yi[4];
            #pragma unroll
            for (int i = 0; i < 4; ++i){
                xr[i] = lr[j*33 + c0 + i]; xi_[i] = li[j*33 + c0 + i];
                yr[i] = lr[j*33 + d0 + i]; yi[i] = li[j*33 + d0 + i];
            }
            #pragma unroll
            for (int ci = 0; ci < 4; ++ci)
                #pragma unroll
                for (int di = 0; di < 4; ++di){
                    are[ci*4+di] += xr[ci]*yr[di] - xi_[ci]*yi[di];
                    aim[ci*4+di] += xr[ci]*yi[di] + xi_[ci]*yr[di];
                }
        }
    }
    float* gb = G + (size_t)bh * 2048;
    #pragma unroll
    for (int ci = 0; ci < 4; ++ci)
        for (int di = 0; di < 4; ++di){
            int idx = ((c0+ci)*32 + d0+di) * 2;
            atomicAdd(gb + idx,     are[ci*4+di]);
            atomicAdd(gb + idx + 1, aim[ci*4+di]);
        }
}

// ---------- K3: normalize, temperature, complex softmax, fold IF32 * (1/524288) ----------
__global__ __launch_bounds__(256) void k_attn(const float* __restrict__ G, const float* __restrict__ norm2,
                                              const float* __restrict__ temp, float* __restrict__ attn2){
    __shared__ float ar[32*33], ai[32*33];
    int bh = blockIdx.x, h = bh & 7, t = threadIdx.x;
    if (t < 32){
        float tv = temp[h];
        float nc = fmaxf(sqrtf(norm2[(bh<<5) + t]), 1e-12f);
        const float* gr = G + (size_t)bh*2048 + t*64;
        float mr = -1e30f, mi = -1e30f;
        for (int d = 0; d < 32; ++d){
            float nd = fmaxf(sqrtf(norm2[(bh<<5) + d]), 1e-12f);
            float s = tv / (nc * nd);
            float vr = gr[d*2] * s, vi = gr[d*2+1] * s;
            ar[t*33+d] = vr; ai[t*33+d] = vi;
            mr = fmaxf(mr, vr); mi = fmaxf(mi, vi);
        }
        float sr = 0.f, si = 0.f;
        for (int d = 0; d < 32; ++d){
            float er = __expf(ar[t*33+d] - mr), ei = __expf(ai[t*33+d] - mi);
            ar[t*33+d] = er; ai[t*33+d] = ei; sr += er; si += ei;
        }
        sr = 1.f/sr; si = 1.f/si;
        for (int d = 0; d < 32; ++d){ ar[t*33+d] *= sr; ai[t*33+d] *= si; }
    }
    __syncthreads();
    const float S = 1.f / 524288.f;
    for (int q = t; q < 1024; q += 256){
        int e = q >> 5, d = q & 31;
        float sr = 0.f, si = 0.f;
        for (int c = 0; c < 32; ++c){
            float sn, cs; sincos_rev((float)((e*c) & 31) * 0.03125f, sn, cs);
            float xr = ar[c*33+d], xi = ai[c*33+d];
            sr += cs*xr - sn*xi;
            si += cs*xi + sn*xr;
        }
        attn2[(size_t)bh*2048 + q*2]     = sr * S;
        attn2[(size_t)bh*2048 + q*2 + 1] = si * S;
    }
}

// ---------- K4: mix[e][n] = sum_d attn2[e][d] * X[d][n]  (complex) ----------
__global__ __launch_bounds__(256) void k_mix(const float* __restrict__ xre, const float* __restrict__ xim,
                                             const float* __restrict__ attn2,
                                             float* __restrict__ ore, float* __restrict__ oim){
    __shared__ float a2[2048];
    __shared__ float lr[32*65], li[32*65];
    int t = threadIdx.x, lane = t & 63, wave = t >> 6;
    int bh = blockIdx.x >> 5;
    int n0 = (blockIdx.x & 31) << 9;
    size_t cbase = (size_t)bh * 32 * NFFT;
    {
        const float4* s4 = (const float4*)(attn2 + (size_t)bh*2048);
        float4* d4 = (float4*)a2;
        d4[t] = s4[t]; d4[t + 256] = s4[t + 256];
    }
    for (int tile = 0; tile < 8; ++tile){
        int nb = n0 + (tile << 6);
        __syncthreads();
        #pragma unroll
        for (int r = 0; r < 8; ++r){
            int ch = (wave << 3) + r;
            lr[ch*65 + lane] = xre[cbase + (size_t)ch*NFFT + nb + lane];
            li[ch*65 + lane] = xim[cbase + (size_t)ch*NFFT + nb + lane];
        }
        __syncthreads();
        float accr[8] = {0,0,0,0,0,0,0,0}, acci[8] = {0,0,0,0,0,0,0,0};
        for (int d = 0; d < 32; d += 2){
            float xr0 = lr[d*65 + lane],     xi0 = li[d*65 + lane];
            float xr1 = lr[(d+1)*65 + lane], xi1 = li[(d+1)*65 + lane];
            #pragma unroll
            for (int k = 0; k < 8; ++k){
                int e = (wave << 3) + k;
                const float4 w = *(const float4*)&a2[(e << 6) + (d << 1)];
                accr[k] += w.x*xr0 - w.y*xi0 + w.z*xr1 - w.w*xi1;
                acci[k] += w.x*xi0 + w.y*xr0 + w.z*xi1 + w.w*xr1;
            }
        }
        #pragma unroll
        for (int k = 0; k < 8; ++k){
            int e = (wave << 3) + k;
            ore[cbase + (size_t)e*NFFT + nb + lane] = accr[k];
            oim[cbase + (size_t)e*NFFT + nb + lane] = acci[k];
        }
    }
}

// ---------- K5: fused 16384-pt inverse FFT (four-step) + abs per row; result into io ----------
__global__ __launch_bounds__(512) void k_ifft_n(const float* ire, float* io){
    __shared__ float sr[128*129], si[128*129];
    int lane = threadIdx.x & 63, wave = threadIdx.x >> 6;
    size_t rb = (size_t)blockIdx.x * NFFT;
    Tw tw; make_tw(tw);
    #pragma unroll 1
    for (int it = 0; it < 16; ++it){
        int jw = (wave << 4) + it;
        size_t base = rb + ((size_t)jw << 7);
        float a0 = ire[base + lane], b0 = io[base + lane];
        float a1 = ire[base + lane + 64], b1 = io[base + lane + 64];
        dit128t(tw, a0, b0, a1, b1);
        int kw = rev7(jw);
        float sn, cs;
        sincos_rev((float)(lane * kw) * 6.103515625e-05f, sn, cs);
        float r = a0*cs - b0*sn, i2 = a0*sn + b0*cs;
        sr[lane*129 + jw] = r; si[lane*129 + jw] = i2;
        sincos_rev((float)((lane + 64) * kw) * 6.103515625e-05f, sn, cs);
        r = a1*cs - b1*sn; i2 = a1*sn + b1*cs;
        sr[(lane+64)*129 + jw] = r; si[(lane+64)*129 + jw] = i2;
    }
    __syncthreads();
    float av[16][2];
    #pragma unroll 1
    for (int it = 0; it < 16; ++it){
        int pw = (wave << 4) + it;
        float a0 = sr[pw*129 + lane],      b0 = si[pw*129 + lane];
        float a1 = sr[pw*129 + lane + 64], b1 = si[pw*129 + lane + 64];
        dit128t(tw, a0, b0, a1, b1);
        av[it][0] = sqrtf(a0*a0 + b0*b0);
        av[it][1] = sqrtf(a1*a1 + b1*b1);
    }
    __syncthreads();
    #pragma unroll 1
    for (int it = 0; it < 16; ++it){
        int pw = (wave << 4) + it;
        sr[lane*129 + pw] = av[it][0];
        sr[(lane+64)*129 + pw] = av[it][1];
    }
    __syncthreads();
    int row = threadIdx.x >> 2, cb = (threadIdx.x & 3) << 5;
    size_t ob = rb + ((size_t)row << 7) + cb;
    const float* s = &sr[row*129 + cb];
    #pragma unroll
    for (int q = 0; q < 8; ++q)
        *(float4*)(io + ob + (q << 2)) = make_float4(s[q*4], s[q*4+1], s[q*4+2], s[q*4+3]);
}

// ---------- K6: gating, IN-PLACE, 4-way split for occupancy ----------
__global__ __launch_bounds__(256) void k_gate(float* xre, float* xim,
                                              const float* __restrict__ w1, const float* __restrict__ b1,
                                              const float* __restrict__ bg, const float* __restrict__ bb_,
                                              const float* __restrict__ bm, const float* __restrict__ bv,
                                              const float* __restrict__ w2, const float* __restrict__ b2){
    __shared__ float w1T[256*17];     // [c][r]
    __shared__ float w2s[256*16];     // [o][r]
    __shared__ float yred[256*17];    // [g*64+col][r]
    int t = threadIdx.x, g = t >> 6, col = t & 63;
    #pragma unroll
    for (int i = 0; i < 16; ++i) w1T[t*17 + i] = w1[i*256 + t];
    {
        const float4* s4 = (const float4*)w2; float4* d4 = (float4*)w2s;
        #pragma unroll
        for (int i = 0; i < 4; ++i) d4[i*256 + t] = s4[i*256 + t];
    }
    __syncthreads();
    int b = blockIdx.x >> 8;
    int n = ((blockIdx.x & 255) << 6) + col;
    size_t base = ((size_t)b << 8) * NFFT + n;
    float y[16];
    #pragma unroll
    for (int r = 0; r < 16; ++r) y[r] = 0.f;
    for (int c = g << 6; c < (g << 6) + 64; ++c){
        float xr = xre[base + (size_t)c*NFFT];
        #pragma unroll
        for (int r = 0; r < 16; ++r) y[r] += w1T[c*17 + r] * xr;
    }
    #pragma unroll
    for (int r = 0; r < 16; ++r) yred[t*17 + r] = y[r];
    __syncthreads();
    #pragma unroll
    for (int r = 0; r < 16; ++r){
        float v = yred[col*17 + r] + yred[(col+64)*17 + r]
                + yred[(col+128)*17 + r] + yred[(col+192)*17 + r] + b1[r];
        v = (v - bm[r]) * rsqrtf(bv[r] + 1e-5f) * bg[r] + bb_[r];
        y[r] = fmaxf(v, 0.f);
    }
    for (int o = g << 6; o < (g << 6) + 64; ++o){
        float s = b2[o];
        #pragma unroll
        for (int r = 0; r < 16; ++r) s += w2s[o*16 + r] * y[r];
        float gg = 1.f / (1.f + __expf(-s)) * 6.103515625e-05f;   // sigmoid * 1/16384
        float xr = xre[base + (size_t)o*NFFT];
        float xi = xim[base + (size_t)o*NFFT];
        xre[base + (size_t)o*NFFT] = gg * xr;
        xim[base + (size_t)o*NFFT] = gg * xi;
    }
}

// ---------- K7: fused ifft2 per image + abs -> re plane ----------
__global__ __launch_bounds__(512) void k_ifft2_gate(float* re_io, const float* im_){
    __shared__ float sr[128*129], si[128*129];
    int lane = threadIdx.x & 63, wave = threadIdx.x >> 6;
    size_t ib = (size_t)blockIdx.x * NFFT;
    Tw tw; make_tw(tw);
    #pragma unroll 1
    for (int it = 0; it < 16; ++it){
        int jw = (wave << 4) + it;
        size_t base = ib + ((size_t)jw << 7);
        float a0 = re_io[base + lane], b0 = im_[base + lane];
        float a1 = re_io[base + lane + 64], b1 = im_[base + lane + 64];
        dit128t(tw, a0, b0, a1, b1);
        sr[lane*129 + jw] = a0;        si[lane*129 + jw] = b0;
        sr[(lane+64)*129 + jw] = a1;   si[(lane+64)*129 + jw] = b1;
    }
    __syncthreads();
    #pragma unroll 1
    for (int it = 0; it < 16; ++it){
        int ph = (wave << 4) + it;
        float a0 = sr[ph*129 + lane],      b0 = si[ph*129 + lane];
        float a1 = sr[ph*129 + lane + 64], b1 = si[ph*129 + lane + 64];
        dit128t(tw, a0, b0, a1, b1);
        size_t o = ib + ((size_t)ph << 7);
        re_io[o + lane]      = sqrtf(a0*a0 + b0*b0);
        re_io[o + lane + 64] = sqrtf(a1*a1 + b1*b1);
    }
}

// ---------- K8: projection via bf16 MFMA, 3-pass hi/lo split ----------
// out[b][o][n] = sum_{q<512} pw[o][q] * cat[b][q][n]; M=256, K=512, N=65536
__device__ __forceinline__ unsigned f2bf(float f){
    unsigned u = __float_as_uint(f);
    return (u + 0x7FFFu + ((u >> 16) & 1u)) >> 16;   // round-to-nearest-even
}
__device__ __forceinline__ float bf2f(unsigned h){
    return __uint_as_float(h << 16);
}
__device__ __forceinline__ void cvt_split8(const float* v, unsigned uh[4], unsigned ul[4]){
    #pragma unroll
    for (int p = 0; p < 4; ++p){
        unsigned h0 = f2bf(v[2*p]),   h1 = f2bf(v[2*p+1]);
        float    l0 = v[2*p]   - bf2f(h0);
        float    l1 = v[2*p+1] - bf2f(h1);
        unsigned g0 = f2bf(l0), g1 = f2bf(l1);
        uh[p] = h0 | (h1 << 16);
        ul[p] = g0 | (g1 << 16);
    }
}
union FU { bf16x8 v; unsigned u[4]; };

__global__ __launch_bounds__(256) void k_proj(const float* __restrict__ cat0, const float* __restrict__ cat1,
                                              const float* __restrict__ pw, float* __restrict__ out){
    __shared__ float As[128*33];   // [o][k], stride 33
    __shared__ float Bs[32*129];   // [k][n], stride 129
    int t = threadIdx.x, lane = t & 63, wave = t >> 6;
    int quad = lane >> 4, l15 = lane & 15;
    int b  = blockIdx.x >> 8;
    int mo = (blockIdx.x >> 7) & 1;          // 0/1 -> o-offset 0/128
    int nt = blockIdx.x & 127;               // n-tile
    int n0 = nt << 7;
    int wr = (wave >> 1) << 6;               // wave m-offset in tile
    int wc = (wave & 1) << 6;                // wave n-offset in tile

    f32x4 acc[4][4];
    #pragma unroll
    for (int i = 0; i < 4; ++i)
        #pragma unroll
        for (int j = 0; j < 4; ++j) acc[i][j] = (f32x4){0.f,0.f,0.f,0.f};

    int ao = t >> 1, ak = (t & 1) << 4;      // A staging: 16 floats each
    int bk = t >> 5, bn = t & 31;            // B staging

    for (int ks = 0; ks < 16; ++ks){
        int k0 = ks << 5;
        __syncthreads();
        {   // stage A: pw[mo*128 + o][k0..k0+31]
            const float* ap = pw + (size_t)((mo << 7) + ao)*512 + k0 + ak;
            #pragma unroll
            for (int i = 0; i < 16; ++i) As[ao*33 + ak + i] = ap[i];
        }
        {   // stage B: cat[b][k0+k][n0 + n]
            #pragma unroll
            for (int p = 0; p < 4; ++p){
                int q = k0 + (p << 3) + bk;
                const float* srow = (q < 256) ? (cat0 + (size_t)((b<<8) + q) * NFFT)
                                              : (cat1 + (size_t)((b<<8) + (q-256)) * NFFT);
                #pragma unroll
                for (int i = 0; i < 4; ++i){
                    int n = bn + (i << 5);
                    Bs[((p<<3) + bk)*129 + n] = srow[n0 + n];
                }
            }
        }
        __syncthreads();
        // fragments
        FU Ah[4], Al[4], Bh[4], Bl[4];
        #pragma unroll
        for (int mi = 0; mi < 4; ++mi){
            float v[8];
            int o = wr + (mi << 4) + l15;
            #pragma unroll
            for (int j = 0; j < 8; ++j) v[j] = As[o*33 + (quad << 3) + j];
            cvt_split8(v, Ah[mi].u, Al[mi].u);
        }
        #pragma unroll
        for (int ni = 0; ni < 4; ++ni){
            float v[8];
            int n = wc + (ni << 4) + l15;
            #pragma unroll
            for (int j = 0; j < 8; ++j) v[j] = Bs[((quad << 3) + j)*129 + n];
            cvt_split8(v, Bh[ni].u, Bl[ni].u);
        }
        #pragma unroll
        for (int mi = 0; mi < 4; ++mi)
            #pragma unroll
            for (int ni = 0; ni < 4; ++ni){
                acc[mi][ni] = __builtin_amdgcn_mfma_f32_16x16x32_bf16(Ah[mi].v, Bh[ni].v, acc[mi][ni], 0, 0, 0);
                acc[mi][ni] = __builtin_amdgcn_mfma_f32_16x16x32_bf16(Ah[mi].v, Bl[ni].v, acc[mi][ni], 0, 0, 0);
                acc[mi][ni] = __builtin_amdgcn_mfma_f32_16x16x32_bf16(Al[mi].v, Bh[ni].v, acc[mi][ni], 0, 0, 0);
            }
    }
    // epilogue: D row = m (quad*4+reg), col = n (lane&15)
    size_t obase = (size_t)((b << 8) + (mo << 7));
    #pragma unroll
    for (int mi = 0; mi < 4; ++mi)
        #pragma unroll
        for (int ni = 0; ni < 4; ++ni){
            int o_ = wr + (mi << 4) + (quad << 2);
            int n_ = n0 + wc + (ni << 4) + l15;
            float* op = out + (obase + o_)*NFFT + n_;
            #pragma unroll
            for (int r = 0; r < 4; ++r) op[(size_t)r*NFFT] = acc[mi][ni][r];
        }
}

// ---------- host ----------
extern "C" void kernel_launch(void* const* d_in, const int* in_sizes, int n_in,
                              void* d_out, int out_size, void* d_ws, size_t ws_size,
                              hipStream_t stream) {
    const float* x    = (const float*)d_in[0];
    const float* temp = (const float*)d_in[1];
    const float* w1   = (const float*)d_in[2];
    const float* b1   = (const float*)d_in[3];
    const float* bg   = (const float*)d_in[4];
    const float* bb_  = (const float*)d_in[5];
    const float* bm   = (const float*)d_in[6];
    const float* bv   = (const float*)d_in[7];
    const float* w2   = (const float*)d_in[8];
    const float* b2   = (const float*)d_in[9];
    const float* pw   = (const float*)d_in[10];
    float* out = (float*)d_out;

    float* ws = (float*)d_ws;
    float* Are  = ws;            // spectrum re -> gated in-place -> cat1
    float* Aim  = ws + NP;       // spectrum im
    float* Ecat = ws + 2*NP;     // mix im -> cat0 (in-place)
    float* norm2 = ws + 3*NP;                  // 1024
    float* G     = norm2 + 1024;               // 65536
    float* attn2 = G + 65536;                  // 65536
    float* mixre = out;                        // d_out doubles as mix-re scratch

    size_t need = (3*NP + 1024 + 65536 + 65536) * sizeof(float);
    if (ws_size < need) return;

    (void)hipMemsetAsync(G, 0, 65536 * sizeof(float), stream);

    k_fft2_fwd<<<1024, 512, 0, stream>>>(x, Are, Aim, norm2);
    k_gram<<<512, 256, 0, stream>>>(Are, Aim, G);
    k_attn<<<32, 256, 0, stream>>>(G, norm2, temp, attn2);
    k_mix<<<1024, 256, 0, stream>>>(Are, Aim, attn2, mixre, Ecat);
    k_ifft_n<<<1024, 512, 0, stream>>>(mixre, Ecat);
    k_gate<<<1024, 256, 0, stream>>>(Are, Aim, w1, b1, bg, bb_, bm, bv, w2, b2);
    k_ifft2_gate<<<1024, 512, 0, stream>>>(Are, Aim);
    k_proj<<<1024, 256, 0, stream>>>(Ecat, Are, pw, out);
    (void)in_sizes; (void)n_in; (void)out_size; (void)ws_size;
}

// Round 5
// 888.892 us; speedup vs baseline: 1.1514x; 1.0631x over previous
//
#include <hip/hip_runtime.h>
#include <math.h>

// Problem constants: b=4, c=256, heads=8, c/head=32, h=w=128, n=16384, cr=16
#define NFFT 16384
static constexpr size_t NP = 16777216; // one plane = 1024 * 16384 floats

typedef short bf16x8 __attribute__((ext_vector_type(8)));
typedef float f32x4  __attribute__((ext_vector_type(4)));

// ---------- helpers ----------
__device__ __forceinline__ void sincos_rev(float rv, float& sn, float& cs){
    sn = __builtin_amdgcn_sinf(rv);   // sin(2*pi*rv)
    cs = __builtin_amdgcn_cosf(rv);
}
__device__ __forceinline__ int rev7(int v){ return (int)(__brev((unsigned)v) >> 25); }

// Per-lane FFT twiddles, hoisted: tw[lg] for stage m=2^lg (lg=0..5), tw[6] for the span-64 stage.
struct Tw { float c[7], s[7]; };
__device__ __forceinline__ void make_tw(Tw& t){
    const int l = threadIdx.x & 63;
    #pragma unroll
    for (int lg = 0; lg < 6; ++lg){
        int m = 1 << lg;
        int e = (l & (m-1)) * (64 >> lg);
        sincos_rev((float)e * 0.0078125f, t.s[lg], t.c[lg]);
    }
    sincos_rev((float)l * 0.0078125f, t.s[6], t.c[6]);
}

// DIF forward: natural in, slot j holds X[rev7(j)] out. W = e^{-2pi i/128}
__device__ __forceinline__ void dif128t(const Tw& t, float& r0, float& i0, float& r1, float& i1){
    const int l = threadIdx.x & 63;
    {   float cs = t.c[6], sn = -t.s[6];
        float ar = r0 + r1, ai = i0 + i1;
        float br = r0 - r1, bi = i0 - i1;
        r0 = ar; i0 = ai;
        r1 = br*cs - bi*sn; i1 = br*sn + bi*cs;
    }
    #pragma unroll
    for (int lg = 5; lg >= 0; --lg){
        int m = 1 << lg;
        float cs = t.c[lg], sn = -t.s[lg];
        bool up = (l & m) != 0;
        float pr = __shfl_xor(r0, m, 64), pi = __shfl_xor(i0, m, 64);
        float tr = up ? (pr - r0) : (r0 + pr);
        float ti = up ? (pi - i0) : (i0 + pi);
        r0 = up ? (tr*cs - ti*sn) : tr;
        i0 = up ? (tr*sn + ti*cs) : ti;
        pr = __shfl_xor(r1, m, 64); pi = __shfl_xor(i1, m, 64);
        tr = up ? (pr - r1) : (r1 + pr);
        ti = up ? (pi - i1) : (i1 + pi);
        r1 = up ? (tr*cs - ti*sn) : tr;
        i1 = up ? (tr*sn + ti*cs) : ti;
    }
}

// DIT inverse (unnormalized): slot j holds X[rev7(j)] in, natural out. W = e^{+2pi i/128}
__device__ __forceinline__ void dit128t(const Tw& t, float& r0, float& i0, float& r1, float& i1){
    const int l = threadIdx.x & 63;
    #pragma unroll
    for (int lg = 0; lg <= 5; ++lg){
        int m = 1 << lg;
        float cs = t.c[lg], sn = t.s[lg];
        bool up = (l & m) != 0;
        float pr = __shfl_xor(r0, m, 64), pi = __shfl_xor(i0, m, 64);
        float vr = up ? r0 : pr, vi = up ? i0 : pi;
        float wr = vr*cs - vi*sn, wi = vr*sn + vi*cs;
        r0 = up ? (pr - wr) : (r0 + wr);
        i0 = up ? (pi - wi) : (i0 + wi);
        pr = __shfl_xor(r1, m, 64); pi = __shfl_xor(i1, m, 64);
        vr = up ? r1 : pr; vi = up ? i1 : pi;
        wr = vr*cs - vi*sn; wi = vr*sn + vi*cs;
        r1 = up ? (pr - wr) : (r1 + wr);
        i1 = up ? (pi - wi) : (i1 + wi);
    }
    {   float cs = t.c[6], sn = t.s[6];
        float wr = r1*cs - i1*sn, wi = r1*sn + i1*cs;
        float ar = r0 + wr, ai = i0 + wi;
        r1 = r0 - wr; i1 = i0 - wi;
        r0 = ar; i0 = ai;
    }
}

// ---------- K1: fused forward fft2 per image. x[img] -> spectrum; norm2[img].
__global__ __launch_bounds__(512) void k_fft2_fwd(const float* __restrict__ x,
                                                  float* __restrict__ ore, float* __restrict__ oim,
                                                  float* __restrict__ norm2){
    __shared__ float sr[128*129], si[128*129];
    __shared__ float red[8];
    int lane = threadIdx.x & 63, wave = threadIdx.x >> 6;
    int img = blockIdx.x;
    Tw tw; make_tw(tw);
    const float* base = x + (size_t)img * NFFT;
    #pragma unroll 1
    for (int it = 0; it < 16; ++it){
        int h = (wave << 4) + it;
        float a0 = base[h*128 + lane], b0 = 0.f;
        float a1 = base[h*128 + lane + 64], b1 = 0.f;
        dif128t(tw, a0, b0, a1, b1);
        sr[lane*129 + h] = a0;        si[lane*129 + h] = b0;
        sr[(lane+64)*129 + h] = a1;   si[(lane+64)*129 + h] = b1;
    }
    __syncthreads();
    float acc = 0.f;
    #pragma unroll 1
    for (int it = 0; it < 16; ++it){
        int j = (wave << 4) + it;
        float a0 = sr[j*129 + lane],      b0 = si[j*129 + lane];
        float a1 = sr[j*129 + lane + 64], b1 = si[j*129 + lane + 64];
        dif128t(tw, a0, b0, a1, b1);
        size_t o = (size_t)img*NFFT + (size_t)j*128;
        ore[o + lane] = a0;      oim[o + lane] = b0;
        ore[o + lane + 64] = a1; oim[o + lane + 64] = b1;
        acc += a0*a0 + b0*b0 + a1*a1 + b1*b1;
    }
    #pragma unroll
    for (int m = 32; m >= 1; m >>= 1) acc += __shfl_xor(acc, m, 64);
    if (lane == 0) red[wave] = acc;
    __syncthreads();
    if (threadIdx.x == 0){
        float s = 0.f;
        #pragma unroll
        for (int i = 0; i < 8; ++i) s += red[i];
        norm2[img] = s;
    }
}

// ---------- K2: gram partials, atomic-free.
// Gpart[(bh*32+chunk)*4 + wave][2048]; partial over n in [chunk*512, chunk*512+512)
__global__ __launch_bounds__(256) void k_gram(const float* __restrict__ xre, const float* __restrict__ xim,
                                              float* __restrict__ Gpart){
    __shared__ float lr[64*36], li[64*36];     // [n_local][ch], stride 36 (16B-aligned reads)
    int t = threadIdx.x, lane = t & 63, wave = t >> 6;
    int bh = blockIdx.x >> 5;
    int n0 = (blockIdx.x & 31) << 9;           // 512-wide chunk
    size_t cbase = (size_t)bh * 32 * NFFT;
    int c0 = (lane >> 3) << 2, d0 = (lane & 7) << 2;
    float are[16], aim[16];
    #pragma unroll
    for (int i = 0; i < 16; ++i){ are[i] = 0.f; aim[i] = 0.f; }
    for (int nt = 0; nt < 8; ++nt){
        int nb = n0 + (nt << 6);
        __syncthreads();
        #pragma unroll
        for (int r = 0; r < 8; ++r){
            int ch = (wave << 3) + r;
            lr[lane*36 + ch] = xre[cbase + (size_t)ch*NFFT + nb + lane];
            li[lane*36 + ch] = xim[cbase + (size_t)ch*NFFT + nb + lane];
        }
        __syncthreads();
        for (int j = (wave<<4); j < (wave<<4) + 16; ++j){
            float4 xr = *(const float4*)&lr[j*36 + c0];
            float4 xi = *(const float4*)&li[j*36 + c0];
            float4 yr = *(const float4*)&lr[j*36 + d0];
            float4 yi = *(const float4*)&li[j*36 + d0];
            const float xrv[4] = {xr.x, xr.y, xr.z, xr.w};
            const float xiv[4] = {xi.x, xi.y, xi.z, xi.w};
            const float yrv[4] = {yr.x, yr.y, yr.z, yr.w};
            const float yiv[4] = {yi.x, yi.y, yi.z, yi.w};
            #pragma unroll
            for (int ci = 0; ci < 4; ++ci)
                #pragma unroll
                for (int di = 0; di < 4; ++di){
                    are[ci*4+di] += xrv[ci]*yrv[di] - xiv[ci]*yiv[di];
                    aim[ci*4+di] += xrv[ci]*yiv[di] + xiv[ci]*yrv[di];
                }
        }
    }
    float* gp = Gpart + ((size_t)blockIdx.x * 4 + wave) * 2048;
    #pragma unroll
    for (int ci = 0; ci < 4; ++ci)
        #pragma unroll
        for (int di = 0; di < 4; ++di){
            int idx = ((c0+ci)*32 + d0+di) * 2;
            gp[idx]     = are[ci*4+di];
            gp[idx + 1] = aim[ci*4+di];
        }
}

// ---------- K2b: reduce 128 partials per bh ----------
__global__ __launch_bounds__(256) void k_gram_red(const float* __restrict__ Gpart, float* __restrict__ G){
    int bh = blockIdx.x >> 3;
    int q  = ((blockIdx.x & 7) << 8) + threadIdx.x;
    const float* gp = Gpart + (size_t)bh * 128 * 2048 + q;
    float s = 0.f;
    #pragma unroll 8
    for (int p = 0; p < 128; ++p) s += gp[(size_t)p * 2048];
    G[(size_t)bh * 2048 + q] = s;
}

// ---------- K3: normalize, temperature, complex softmax, fold IF32 * (1/524288) ----------
__global__ __launch_bounds__(256) void k_attn(const float* __restrict__ G, const float* __restrict__ norm2,
                                              const float* __restrict__ temp, float* __restrict__ attn2){
    __shared__ float ar[32*33], ai[32*33];
    int bh = blockIdx.x, h = bh & 7, t = threadIdx.x;
    if (t < 32){
        float tv = temp[h];
        float nc = fmaxf(sqrtf(norm2[(bh<<5) + t]), 1e-12f);
        const float* gr = G + (size_t)bh*2048 + t*64;
        float mr = -1e30f, mi = -1e30f;
        for (int d = 0; d < 32; ++d){
            float nd = fmaxf(sqrtf(norm2[(bh<<5) + d]), 1e-12f);
            float s = tv / (nc * nd);
            float vr = gr[d*2] * s, vi = gr[d*2+1] * s;
            ar[t*33+d] = vr; ai[t*33+d] = vi;
            mr = fmaxf(mr, vr); mi = fmaxf(mi, vi);
        }
        float sr = 0.f, si = 0.f;
        for (int d = 0; d < 32; ++d){
            float er = __expf(ar[t*33+d] - mr), ei = __expf(ai[t*33+d] - mi);
            ar[t*33+d] = er; ai[t*33+d] = ei; sr += er; si += ei;
        }
        sr = 1.f/sr; si = 1.f/si;
        for (int d = 0; d < 32; ++d){ ar[t*33+d] *= sr; ai[t*33+d] *= si; }
    }
    __syncthreads();
    const float S = 1.f / 524288.f;
    for (int q = t; q < 1024; q += 256){
        int e = q >> 5, d = q & 31;
        float sr = 0.f, si = 0.f;
        for (int c = 0; c < 32; ++c){
            float sn, cs; sincos_rev((float)((e*c) & 31) * 0.03125f, sn, cs);
            float xr = ar[c*33+d], xi = ai[c*33+d];
            sr += cs*xr - sn*xi;
            si += cs*xi + sn*xr;
        }
        attn2[(size_t)bh*2048 + q*2]     = sr * S;
        attn2[(size_t)bh*2048 + q*2 + 1] = si * S;
    }
}

// ---------- K4: mix[e][n] = sum_d attn2[e][d] * X[d][n]  (complex) ----------
__global__ __launch_bounds__(256) void k_mix(const float* __restrict__ xre, const float* __restrict__ xim,
                                             const float* __restrict__ attn2,
                                             float* __restrict__ ore, float* __restrict__ oim){
    __shared__ float a2[2048];
    __shared__ float lr[32*65], li[32*65];
    int t = threadIdx.x, lane = t & 63, wave = t >> 6;
    int bh = blockIdx.x >> 5;
    int n0 = (blockIdx.x & 31) << 9;
    size_t cbase = (size_t)bh * 32 * NFFT;
    {
        const float4* s4 = (const float4*)(attn2 + (size_t)bh*2048);
        float4* d4 = (float4*)a2;
        d4[t] = s4[t]; d4[t + 256] = s4[t + 256];
    }
    for (int tile = 0; tile < 8; ++tile){
        int nb = n0 + (tile << 6);
        __syncthreads();
        #pragma unroll
        for (int r = 0; r < 8; ++r){
            int ch = (wave << 3) + r;
            lr[ch*65 + lane] = xre[cbase + (size_t)ch*NFFT + nb + lane];
            li[ch*65 + lane] = xim[cbase + (size_t)ch*NFFT + nb + lane];
        }
        __syncthreads();
        float accr[8] = {0,0,0,0,0,0,0,0}, acci[8] = {0,0,0,0,0,0,0,0};
        for (int d = 0; d < 32; d += 2){
            float xr0 = lr[d*65 + lane],     xi0 = li[d*65 + lane];
            float xr1 = lr[(d+1)*65 + lane], xi1 = li[(d+1)*65 + lane];
            #pragma unroll
            for (int k = 0; k < 8; ++k){
                int e = (wave << 3) + k;
                const float4 w = *(const float4*)&a2[(e << 6) + (d << 1)];
                accr[k] += w.x*xr0 - w.y*xi0 + w.z*xr1 - w.w*xi1;
                acci[k] += w.x*xi0 + w.y*xr0 + w.z*xi1 + w.w*xr1;
            }
        }
        #pragma unroll
        for (int k = 0; k < 8; ++k){
            int e = (wave << 3) + k;
            ore[cbase + (size_t)e*NFFT + nb + lane] = accr[k];
            oim[cbase + (size_t)e*NFFT + nb + lane] = acci[k];
        }
    }
}

// ---------- K5: fused 16384-pt inverse FFT (four-step) + abs per row; result into io ----------
__global__ __launch_bounds__(512) void k_ifft_n(const float* ire, float* io){
    __shared__ float sr[128*129], si[128*129];
    int lane = threadIdx.x & 63, wave = threadIdx.x >> 6;
    size_t rb = (size_t)blockIdx.x * NFFT;
    Tw tw; make_tw(tw);
    #pragma unroll 1
    for (int it = 0; it < 16; ++it){
        int jw = (wave << 4) + it;
        size_t base = rb + ((size_t)jw << 7);
        float a0 = ire[base + lane], b0 = io[base + lane];
        float a1 = ire[base + lane + 64], b1 = io[base + lane + 64];
        dit128t(tw, a0, b0, a1, b1);
        int kw = rev7(jw);
        float sn, cs;
        sincos_rev((float)(lane * kw) * 6.103515625e-05f, sn, cs);
        float r = a0*cs - b0*sn, i2 = a0*sn + b0*cs;
        sr[lane*129 + jw] = r; si[lane*129 + jw] = i2;
        sincos_rev((float)((lane + 64) * kw) * 6.103515625e-05f, sn, cs);
        r = a1*cs - b1*sn; i2 = a1*sn + b1*cs;
        sr[(lane+64)*129 + jw] = r; si[(lane+64)*129 + jw] = i2;
    }
    __syncthreads();
    float av[16][2];
    #pragma unroll 1
    for (int it = 0; it < 16; ++it){
        int pw = (wave << 4) + it;
        float a0 = sr[pw*129 + lane],      b0 = si[pw*129 + lane];
        float a1 = sr[pw*129 + lane + 64], b1 = si[pw*129 + lane + 64];
        dit128t(tw, a0, b0, a1, b1);
        av[it][0] = sqrtf(a0*a0 + b0*b0);
        av[it][1] = sqrtf(a1*a1 + b1*b1);
    }
    __syncthreads();
    #pragma unroll 1
    for (int it = 0; it < 16; ++it){
        int pw = (wave << 4) + it;
        sr[lane*129 + pw] = av[it][0];
        sr[(lane+64)*129 + pw] = av[it][1];
    }
    __syncthreads();
    int row = threadIdx.x >> 2, cb = (threadIdx.x & 3) << 5;
    size_t ob = rb + ((size_t)row << 7) + cb;
    const float* s = &sr[row*129 + cb];
    #pragma unroll
    for (int q = 0; q < 8; ++q)
        *(float4*)(io + ob + (q << 2)) = make_float4(s[q*4], s[q*4+1], s[q*4+2], s[q*4+3]);
}

// ---------- K6: gating, IN-PLACE, 4-way split for occupancy ----------
__global__ __launch_bounds__(256) void k_gate(float* xre, float* xim,
                                              const float* __restrict__ w1, const float* __restrict__ b1,
                                              const float* __restrict__ bg, const float* __restrict__ bb_,
                                              const float* __restrict__ bm, const float* __restrict__ bv,
                                              const float* __restrict__ w2, const float* __restrict__ b2){
    __shared__ float w1T[256*17];     // [c][r]
    __shared__ float w2s[256*16];     // [o][r]
    __shared__ float yred[256*17];    // [g*64+col][r]
    int t = threadIdx.x, g = t >> 6, col = t & 63;
    #pragma unroll
    for (int i = 0; i < 16; ++i) w1T[t*17 + i] = w1[i*256 + t];
    {
        const float4* s4 = (const float4*)w2; float4* d4 = (float4*)w2s;
        #pragma unroll
        for (int i = 0; i < 4; ++i) d4[i*256 + t] = s4[i*256 + t];
    }
    __syncthreads();
    int b = blockIdx.x >> 8;
    int n = ((blockIdx.x & 255) << 6) + col;
    size_t base = ((size_t)b << 8) * NFFT + n;
    float y[16];
    #pragma unroll
    for (int r = 0; r < 16; ++r) y[r] = 0.f;
    for (int c = g << 6; c < (g << 6) + 64; ++c){
        float xr = xre[base + (size_t)c*NFFT];
        #pragma unroll
        for (int r = 0; r < 16; ++r) y[r] += w1T[c*17 + r] * xr;
    }
    #pragma unroll
    for (int r = 0; r < 16; ++r) yred[t*17 + r] = y[r];
    __syncthreads();
    #pragma unroll
    for (int r = 0; r < 16; ++r){
        float v = yred[col*17 + r] + yred[(col+64)*17 + r]
                + yred[(col+128)*17 + r] + yred[(col+192)*17 + r] + b1[r];
        v = (v - bm[r]) * rsqrtf(bv[r] + 1e-5f) * bg[r] + bb_[r];
        y[r] = fmaxf(v, 0.f);
    }
    for (int o = g << 6; o < (g << 6) + 64; ++o){
        float s = b2[o];
        #pragma unroll
        for (int r = 0; r < 16; ++r) s += w2s[o*16 + r] * y[r];
        float gg = 1.f / (1.f + __expf(-s)) * 6.103515625e-05f;   // sigmoid * 1/16384
        float xr = xre[base + (size_t)o*NFFT];
        float xi = xim[base + (size_t)o*NFFT];
        xre[base + (size_t)o*NFFT] = gg * xr;
        xim[base + (size_t)o*NFFT] = gg * xi;
    }
}

// ---------- K7: fused ifft2 per image + abs -> re plane ----------
__global__ __launch_bounds__(512) void k_ifft2_gate(float* re_io, const float* im_){
    __shared__ float sr[128*129], si[128*129];
    int lane = threadIdx.x & 63, wave = threadIdx.x >> 6;
    size_t ib = (size_t)blockIdx.x * NFFT;
    Tw tw; make_tw(tw);
    #pragma unroll 1
    for (int it = 0; it < 16; ++it){
        int jw = (wave << 4) + it;
        size_t base = ib + ((size_t)jw << 7);
        float a0 = re_io[base + lane], b0 = im_[base + lane];
        float a1 = re_io[base + lane + 64], b1 = im_[base + lane + 64];
        dit128t(tw, a0, b0, a1, b1);
        sr[lane*129 + jw] = a0;        si[lane*129 + jw] = b0;
        sr[(lane+64)*129 + jw] = a1;   si[(lane+64)*129 + jw] = b1;
    }
    __syncthreads();
    #pragma unroll 1
    for (int it = 0; it < 16; ++it){
        int ph = (wave << 4) + it;
        float a0 = sr[ph*129 + lane],      b0 = si[ph*129 + lane];
        float a1 = sr[ph*129 + lane + 64], b1 = si[ph*129 + lane + 64];
        dit128t(tw, a0, b0, a1, b1);
        size_t o = ib + ((size_t)ph << 7);
        re_io[o + lane]      = sqrtf(a0*a0 + b0*b0);
        re_io[o + lane + 64] = sqrtf(a1*a1 + b1*b1);
    }
}

// ---------- K8: projection via bf16 MFMA, 3-pass hi/lo split ----------
__device__ __forceinline__ unsigned f2bf(float f){
    unsigned u = __float_as_uint(f);
    return (u + 0x7FFFu + ((u >> 16) & 1u)) >> 16;   // round-to-nearest-even
}
__device__ __forceinline__ float bf2f(unsigned h){
    return __uint_as_float(h << 16);
}
__device__ __forceinline__ void cvt_split8(const float* v, unsigned uh[4], unsigned ul[4]){
    #pragma unroll
    for (int p = 0; p < 4; ++p){
        unsigned h0 = f2bf(v[2*p]),   h1 = f2bf(v[2*p+1]);
        float    l0 = v[2*p]   - bf2f(h0);
        float    l1 = v[2*p+1] - bf2f(h1);
        unsigned g0 = f2bf(l0), g1 = f2bf(l1);
        uh[p] = h0 | (h1 << 16);
        ul[p] = g0 | (g1 << 16);
    }
}
union FU { bf16x8 v; unsigned u[4]; };

__global__ __launch_bounds__(256) void k_proj(const float* __restrict__ cat0, const float* __restrict__ cat1,
                                              const float* __restrict__ pw, float* __restrict__ out){
    __shared__ float As[128*33];   // [o][k], stride 33
    __shared__ float Bs[32*129];   // [k][n], stride 129
    int t = threadIdx.x, lane = t & 63, wave = t >> 6;
    int quad = lane >> 4, l15 = lane & 15;
    int b  = blockIdx.x >> 8;
    int mo = (blockIdx.x >> 7) & 1;
    int nt = blockIdx.x & 127;
    int n0 = nt << 7;
    int wr = (wave >> 1) << 6;
    int wc = (wave & 1) << 6;

    f32x4 acc[4][4];
    #pragma unroll
    for (int i = 0; i < 4; ++i)
        #pragma unroll
        for (int j = 0; j < 4; ++j) acc[i][j] = (f32x4){0.f,0.f,0.f,0.f};

    int ao = t >> 1, ak = (t & 1) << 4;
    int bk = t >> 5, bn = t & 31;

    for (int ks = 0; ks < 16; ++ks){
        int k0 = ks << 5;
        __syncthreads();
        {
            const float* ap = pw + (size_t)((mo << 7) + ao)*512 + k0 + ak;
            #pragma unroll
            for (int i = 0; i < 16; ++i) As[ao*33 + ak + i] = ap[i];
        }
        {
            #pragma unroll
            for (int p = 0; p < 4; ++p){
                int q = k0 + (p << 3) + bk;
                const float* srow = (q < 256) ? (cat0 + (size_t)((b<<8) + q) * NFFT)
                                              : (cat1 + (size_t)((b<<8) + (q-256)) * NFFT);
                #pragma unroll
                for (int i = 0; i < 4; ++i){
                    int n = bn + (i << 5);
                    Bs[((p<<3) + bk)*129 + n] = srow[n0 + n];
                }
            }
        }
        __syncthreads();
        FU Ah[4], Al[4], Bh[4], Bl[4];
        #pragma unroll
        for (int mi = 0; mi < 4; ++mi){
            float v[8];
            int o = wr + (mi << 4) + l15;
            #pragma unroll
            for (int j = 0; j < 8; ++j) v[j] = As[o*33 + (quad << 3) + j];
            cvt_split8(v, Ah[mi].u, Al[mi].u);
        }
        #pragma unroll
        for (int ni = 0; ni < 4; ++ni){
            float v[8];
            int n = wc + (ni << 4) + l15;
            #pragma unroll
            for (int j = 0; j < 8; ++j) v[j] = Bs[((quad << 3) + j)*129 + n];
            cvt_split8(v, Bh[ni].u, Bl[ni].u);
        }
        #pragma unroll
        for (int mi = 0; mi < 4; ++mi)
            #pragma unroll
            for (int ni = 0; ni < 4; ++ni){
                acc[mi][ni] = __builtin_amdgcn_mfma_f32_16x16x32_bf16(Ah[mi].v, Bh[ni].v, acc[mi][ni], 0, 0, 0);
                acc[mi][ni] = __builtin_amdgcn_mfma_f32_16x16x32_bf16(Ah[mi].v, Bl[ni].v, acc[mi][ni], 0, 0, 0);
                acc[mi][ni] = __builtin_amdgcn_mfma_f32_16x16x32_bf16(Al[mi].v, Bh[ni].v, acc[mi][ni], 0, 0, 0);
            }
    }
    size_t obase = (size_t)((b << 8) + (mo << 7));
    #pragma unroll
    for (int mi = 0; mi < 4; ++mi)
        #pragma unroll
        for (int ni = 0; ni < 4; ++ni){
            int o_ = wr + (mi << 4) + (quad << 2);
            int n_ = n0 + wc + (ni << 4) + l15;
            float* op = out + (obase + o_)*NFFT + n_;
            #pragma unroll
            for (int r = 0; r < 4; ++r) op[(size_t)r*NFFT] = acc[mi][ni][r];
        }
}

// ---------- host ----------
extern "C" void kernel_launch(void* const* d_in, const int* in_sizes, int n_in,
                              void* d_out, int out_size, void* d_ws, size_t ws_size,
                              hipStream_t stream) {
    const float* x    = (const float*)d_in[0];
    const float* temp = (const float*)d_in[1];
    const float* w1   = (const float*)d_in[2];
    const float* b1   = (const float*)d_in[3];
    const float* bg   = (const float*)d_in[4];
    const float* bb_  = (const float*)d_in[5];
    const float* bm   = (const float*)d_in[6];
    const float* bv   = (const float*)d_in[7];
    const float* w2   = (const float*)d_in[8];
    const float* b2   = (const float*)d_in[9];
    const float* pw   = (const float*)d_in[10];
    float* out = (float*)d_out;

    float* ws = (float*)d_ws;
    float* Are  = ws;            // spectrum re -> gated in-place -> cat1
    float* Aim  = ws + NP;       // spectrum im
    float* Ecat = ws + 2*NP;     // Gpart scratch -> mix im -> cat0 (in-place)
    float* norm2 = ws + 3*NP;                  // 1024
    float* G     = norm2 + 1024;               // 65536
    float* attn2 = G + 65536;                  // 65536
    float* mixre = out;                        // d_out doubles as mix-re scratch
    float* Gpart = Ecat;                       // 8.4M floats, dead until k_mix

    size_t need = (3*NP + 1024 + 65536 + 65536) * sizeof(float);
    if (ws_size < need) return;

    k_fft2_fwd<<<1024, 512, 0, stream>>>(x, Are, Aim, norm2);
    k_gram<<<1024, 256, 0, stream>>>(Are, Aim, Gpart);
    k_gram_red<<<256, 256, 0, stream>>>(Gpart, G);
    k_attn<<<32, 256, 0, stream>>>(G, norm2, temp, attn2);
    k_mix<<<1024, 256, 0, stream>>>(Are, Aim, attn2, mixre, Ecat);
    k_ifft_n<<<1024, 512, 0, stream>>>(mixre, Ecat);
    k_gate<<<1024, 256, 0, stream>>>(Are, Aim, w1, b1, bg, bb_, bm, bv, w2, b2);
    k_ifft2_gate<<<1024, 512, 0, stream>>>(Are, Aim);
    k_proj<<<1024, 256, 0, stream>>>(Ecat, Are, pw, out);
    (void)in_sizes; (void)n_in; (void)out_size; (void)ws_size;
}

// Round 6
// 827.290 us; speedup vs baseline: 1.2371x; 1.0745x over previous
//
#include <hip/hip_runtime.h>
#include <math.h>

// Problem constants: b=4, c=256, heads=8, c/head=32, h=w=128, n=16384, cr=16
#define NFFT 16384
static constexpr size_t NP = 16777216; // one plane = 1024 * 16384 floats

typedef short bf16x8 __attribute__((ext_vector_type(8)));
typedef float f32x4  __attribute__((ext_vector_type(4)));

// ---------- helpers ----------
__device__ __forceinline__ void sincos_rev(float rv, float& sn, float& cs){
    sn = __builtin_amdgcn_sinf(rv);   // sin(2*pi*rv)
    cs = __builtin_amdgcn_cosf(rv);
}
__device__ __forceinline__ int rev7(int v){ return (int)(__brev((unsigned)v) >> 25); }

__device__ __forceinline__ unsigned f2bf(float f){
    unsigned u = __float_as_uint(f);
    return (u + 0x7FFFu + ((u >> 16) & 1u)) >> 16;   // round-to-nearest-even
}
__device__ __forceinline__ float bf2f(unsigned h){ return __uint_as_float(h << 16); }
// pack fp32 -> (bf16 hi | bf16 lo) in one u32, stored via float bit-pattern
__device__ __forceinline__ unsigned packsplit(float v){
    unsigned h = f2bf(v);
    float r = v - bf2f(h);
    unsigned l = f2bf(r);
    return (h << 16) | l;
}

// Per-lane FFT twiddles, hoisted.
struct Tw { float c[7], s[7]; };
__device__ __forceinline__ void make_tw(Tw& t){
    const int l = threadIdx.x & 63;
    #pragma unroll
    for (int lg = 0; lg < 6; ++lg){
        int m = 1 << lg;
        int e = (l & (m-1)) * (64 >> lg);
        sincos_rev((float)e * 0.0078125f, t.s[lg], t.c[lg]);
    }
    sincos_rev((float)l * 0.0078125f, t.s[6], t.c[6]);
}

// DIF forward: natural in, slot j holds X[rev7(j)] out. W = e^{-2pi i/128}
__device__ __forceinline__ void dif128t(const Tw& t, float& r0, float& i0, float& r1, float& i1){
    const int l = threadIdx.x & 63;
    {   float cs = t.c[6], sn = -t.s[6];
        float ar = r0 + r1, ai = i0 + i1;
        float br = r0 - r1, bi = i0 - i1;
        r0 = ar; i0 = ai;
        r1 = br*cs - bi*sn; i1 = br*sn + bi*cs;
    }
    #pragma unroll
    for (int lg = 5; lg >= 0; --lg){
        int m = 1 << lg;
        float cs = t.c[lg], sn = -t.s[lg];
        bool up = (l & m) != 0;
        float pr = __shfl_xor(r0, m, 64), pi = __shfl_xor(i0, m, 64);
        float tr = up ? (pr - r0) : (r0 + pr);
        float ti = up ? (pi - i0) : (i0 + pi);
        r0 = up ? (tr*cs - ti*sn) : tr;
        i0 = up ? (tr*sn + ti*cs) : ti;
        pr = __shfl_xor(r1, m, 64); pi = __shfl_xor(i1, m, 64);
        tr = up ? (pr - r1) : (r1 + pr);
        ti = up ? (pi - i1) : (i1 + pi);
        r1 = up ? (tr*cs - ti*sn) : tr;
        i1 = up ? (tr*sn + ti*cs) : ti;
    }
}

// DIT inverse (unnormalized): slot j holds X[rev7(j)] in, natural out. W = e^{+2pi i/128}
__device__ __forceinline__ void dit128t(const Tw& t, float& r0, float& i0, float& r1, float& i1){
    const int l = threadIdx.x & 63;
    #pragma unroll
    for (int lg = 0; lg <= 5; ++lg){
        int m = 1 << lg;
        float cs = t.c[lg], sn = t.s[lg];
        bool up = (l & m) != 0;
        float pr = __shfl_xor(r0, m, 64), pi = __shfl_xor(i0, m, 64);
        float vr = up ? r0 : pr, vi = up ? i0 : pi;
        float wr = vr*cs - vi*sn, wi = vr*sn + vi*cs;
        r0 = up ? (pr - wr) : (r0 + wr);
        i0 = up ? (pi - wi) : (i0 + wi);
        pr = __shfl_xor(r1, m, 64); pi = __shfl_xor(i1, m, 64);
        vr = up ? r1 : pr; vi = up ? i1 : pi;
        wr = vr*cs - vi*sn; wi = vr*sn + vi*cs;
        r1 = up ? (pr - wr) : (r1 + wr);
        i1 = up ? (pi - wi) : (i1 + wi);
    }
    {   float cs = t.c[6], sn = t.s[6];
        float wr = r1*cs - i1*sn, wi = r1*sn + i1*cs;
        float ar = r0 + wr, ai = i0 + wi;
        r1 = r0 - wr; i1 = i0 - wi;
        r0 = ar; i0 = ai;
    }
}

// ---------- K1: fused forward fft2 per image. x[img] -> spectrum; norm2[img].
__global__ __launch_bounds__(512) void k_fft2_fwd(const float* __restrict__ x,
                                                  float* __restrict__ ore, float* __restrict__ oim,
                                                  float* __restrict__ norm2){
    __shared__ float sr[128*129], si[128*129];
    __shared__ float red[8];
    int lane = threadIdx.x & 63, wave = threadIdx.x >> 6;
    int img = blockIdx.x;
    Tw tw; make_tw(tw);
    const float* base = x + (size_t)img * NFFT;
    #pragma unroll 1
    for (int it = 0; it < 16; ++it){
        int h = (wave << 4) + it;
        float a0 = base[h*128 + lane], b0 = 0.f;
        float a1 = base[h*128 + lane + 64], b1 = 0.f;
        dif128t(tw, a0, b0, a1, b1);
        sr[lane*129 + h] = a0;        si[lane*129 + h] = b0;
        sr[(lane+64)*129 + h] = a1;   si[(lane+64)*129 + h] = b1;
    }
    __syncthreads();
    float acc = 0.f;
    #pragma unroll 1
    for (int it = 0; it < 16; ++it){
        int j = (wave << 4) + it;
        float a0 = sr[j*129 + lane],      b0 = si[j*129 + lane];
        float a1 = sr[j*129 + lane + 64], b1 = si[j*129 + lane + 64];
        dif128t(tw, a0, b0, a1, b1);
        size_t o = (size_t)img*NFFT + (size_t)j*128;
        ore[o + lane] = a0;      oim[o + lane] = b0;
        ore[o + lane + 64] = a1; oim[o + lane + 64] = b1;
        acc += a0*a0 + b0*b0 + a1*a1 + b1*b1;
    }
    #pragma unroll
    for (int m = 32; m >= 1; m >>= 1) acc += __shfl_xor(acc, m, 64);
    if (lane == 0) red[wave] = acc;
    __syncthreads();
    if (threadIdx.x == 0){
        float s = 0.f;
        #pragma unroll
        for (int i = 0; i < 8; ++i) s += red[i];
        norm2[img] = s;
    }
}

// ---------- K2: gram partials, atomic-free ----------
__global__ __launch_bounds__(256) void k_gram(const float* __restrict__ xre, const float* __restrict__ xim,
                                              float* __restrict__ Gpart){
    __shared__ float lr[64*36], li[64*36];
    int t = threadIdx.x, lane = t & 63, wave = t >> 6;
    int bh = blockIdx.x >> 5;
    int n0 = (blockIdx.x & 31) << 9;
    size_t cbase = (size_t)bh * 32 * NFFT;
    int c0 = (lane >> 3) << 2, d0 = (lane & 7) << 2;
    float are[16], aim[16];
    #pragma unroll
    for (int i = 0; i < 16; ++i){ are[i] = 0.f; aim[i] = 0.f; }
    for (int nt = 0; nt < 8; ++nt){
        int nb = n0 + (nt << 6);
        __syncthreads();
        #pragma unroll
        for (int r = 0; r < 8; ++r){
            int ch = (wave << 3) + r;
            lr[lane*36 + ch] = xre[cbase + (size_t)ch*NFFT + nb + lane];
            li[lane*36 + ch] = xim[cbase + (size_t)ch*NFFT + nb + lane];
        }
        __syncthreads();
        for (int j = (wave<<4); j < (wave<<4) + 16; ++j){
            float4 xr = *(const float4*)&lr[j*36 + c0];
            float4 xi = *(const float4*)&li[j*36 + c0];
            float4 yr = *(const float4*)&lr[j*36 + d0];
            float4 yi = *(const float4*)&li[j*36 + d0];
            const float xrv[4] = {xr.x, xr.y, xr.z, xr.w};
            const float xiv[4] = {xi.x, xi.y, xi.z, xi.w};
            const float yrv[4] = {yr.x, yr.y, yr.z, yr.w};
            const float yiv[4] = {yi.x, yi.y, yi.z, yi.w};
            #pragma unroll
            for (int ci = 0; ci < 4; ++ci)
                #pragma unroll
                for (int di = 0; di < 4; ++di){
                    are[ci*4+di] += xrv[ci]*yrv[di] - xiv[ci]*yiv[di];
                    aim[ci*4+di] += xrv[ci]*yiv[di] + xiv[ci]*yrv[di];
                }
        }
    }
    float* gp = Gpart + ((size_t)blockIdx.x * 4 + wave) * 2048;
    #pragma unroll
    for (int ci = 0; ci < 4; ++ci)
        #pragma unroll
        for (int di = 0; di < 4; ++di){
            int idx = ((c0+ci)*32 + d0+di) * 2;
            gp[idx]     = are[ci*4+di];
            gp[idx + 1] = aim[ci*4+di];
        }
}

// ---------- K2b: reduce 128 partials per bh ----------
__global__ __launch_bounds__(256) void k_gram_red(const float* __restrict__ Gpart, float* __restrict__ G){
    int bh = blockIdx.x >> 3;
    int q  = ((blockIdx.x & 7) << 8) + threadIdx.x;
    const float* gp = Gpart + (size_t)bh * 128 * 2048 + q;
    float s = 0.f;
    #pragma unroll 8
    for (int p = 0; p < 128; ++p) s += gp[(size_t)p * 2048];
    G[(size_t)bh * 2048 + q] = s;
}

// ---------- K3: normalize, temperature, complex softmax, fold IF32 * (1/524288) ----------
__global__ __launch_bounds__(256) void k_attn(const float* __restrict__ G, const float* __restrict__ norm2,
                                              const float* __restrict__ temp, float* __restrict__ attn2){
    __shared__ float ar[32*33], ai[32*33];
    int bh = blockIdx.x, h = bh & 7, t = threadIdx.x;
    if (t < 32){
        float tv = temp[h];
        float nc = fmaxf(sqrtf(norm2[(bh<<5) + t]), 1e-12f);
        const float* gr = G + (size_t)bh*2048 + t*64;
        float mr = -1e30f, mi = -1e30f;
        for (int d = 0; d < 32; ++d){
            float nd = fmaxf(sqrtf(norm2[(bh<<5) + d]), 1e-12f);
            float s = tv / (nc * nd);
            float vr = gr[d*2] * s, vi = gr[d*2+1] * s;
            ar[t*33+d] = vr; ai[t*33+d] = vi;
            mr = fmaxf(mr, vr); mi = fmaxf(mi, vi);
        }
        float sr = 0.f, si = 0.f;
        for (int d = 0; d < 32; ++d){
            float er = __expf(ar[t*33+d] - mr), ei = __expf(ai[t*33+d] - mi);
            ar[t*33+d] = er; ai[t*33+d] = ei; sr += er; si += ei;
        }
        sr = 1.f/sr; si = 1.f/si;
        for (int d = 0; d < 32; ++d){ ar[t*33+d] *= sr; ai[t*33+d] *= si; }
    }
    __syncthreads();
    const float S = 1.f / 524288.f;
    for (int q = t; q < 1024; q += 256){
        int e = q >> 5, d = q & 31;
        float sr = 0.f, si = 0.f;
        for (int c = 0; c < 32; ++c){
            float sn, cs; sincos_rev((float)((e*c) & 31) * 0.03125f, sn, cs);
            float xr = ar[c*33+d], xi = ai[c*33+d];
            sr += cs*xr - sn*xi;
            si += cs*xi + sn*xr;
        }
        attn2[(size_t)bh*2048 + q*2]     = sr * S;
        attn2[(size_t)bh*2048 + q*2 + 1] = si * S;
    }
}

// ---------- K4: mix[e][n] = sum_d attn2[e][d] * X[d][n]  (complex) ----------
__global__ __launch_bounds__(256) void k_mix(const float* __restrict__ xre, const float* __restrict__ xim,
                                             const float* __restrict__ attn2,
                                             float* __restrict__ ore, float* __restrict__ oim){
    __shared__ float a2[2048];
    __shared__ float lr[32*65], li[32*65];
    int t = threadIdx.x, lane = t & 63, wave = t >> 6;
    int bh = blockIdx.x >> 5;
    int n0 = (blockIdx.x & 31) << 9;
    size_t cbase = (size_t)bh * 32 * NFFT;
    {
        const float4* s4 = (const float4*)(attn2 + (size_t)bh*2048);
        float4* d4 = (float4*)a2;
        d4[t] = s4[t]; d4[t + 256] = s4[t + 256];
    }
    for (int tile = 0; tile < 8; ++tile){
        int nb = n0 + (tile << 6);
        __syncthreads();
        #pragma unroll
        for (int r = 0; r < 8; ++r){
            int ch = (wave << 3) + r;
            lr[ch*65 + lane] = xre[cbase + (size_t)ch*NFFT + nb + lane];
            li[ch*65 + lane] = xim[cbase + (size_t)ch*NFFT + nb + lane];
        }
        __syncthreads();
        float accr[8] = {0,0,0,0,0,0,0,0}, acci[8] = {0,0,0,0,0,0,0,0};
        for (int d = 0; d < 32; d += 2){
            float xr0 = lr[d*65 + lane],     xi0 = li[d*65 + lane];
            float xr1 = lr[(d+1)*65 + lane], xi1 = li[(d+1)*65 + lane];
            #pragma unroll
            for (int k = 0; k < 8; ++k){
                int e = (wave << 3) + k;
                const float4 w = *(const float4*)&a2[(e << 6) + (d << 1)];
                accr[k] += w.x*xr0 - w.y*xi0 + w.z*xr1 - w.w*xi1;
                acci[k] += w.x*xi0 + w.y*xr0 + w.z*xi1 + w.w*xr1;
            }
        }
        #pragma unroll
        for (int k = 0; k < 8; ++k){
            int e = (wave << 3) + k;
            ore[cbase + (size_t)e*NFFT + nb + lane] = accr[k];
            oim[cbase + (size_t)e*NFFT + nb + lane] = acci[k];
        }
    }
}

// ---------- K5: fused 16384-pt inverse FFT + abs per row; PACKED bf16(hi|lo) into io ----------
__global__ __launch_bounds__(512) void k_ifft_n(const float* ire, float* io){
    __shared__ float sr[128*129], si[128*129];
    int lane = threadIdx.x & 63, wave = threadIdx.x >> 6;
    size_t rb = (size_t)blockIdx.x * NFFT;
    Tw tw; make_tw(tw);
    #pragma unroll 1
    for (int it = 0; it < 16; ++it){
        int jw = (wave << 4) + it;
        size_t base = rb + ((size_t)jw << 7);
        float a0 = ire[base + lane], b0 = io[base + lane];
        float a1 = ire[base + lane + 64], b1 = io[base + lane + 64];
        dit128t(tw, a0, b0, a1, b1);
        int kw = rev7(jw);
        float sn, cs;
        sincos_rev((float)(lane * kw) * 6.103515625e-05f, sn, cs);
        float r = a0*cs - b0*sn, i2 = a0*sn + b0*cs;
        sr[lane*129 + jw] = r; si[lane*129 + jw] = i2;
        sincos_rev((float)((lane + 64) * kw) * 6.103515625e-05f, sn, cs);
        r = a1*cs - b1*sn; i2 = a1*sn + b1*cs;
        sr[(lane+64)*129 + jw] = r; si[(lane+64)*129 + jw] = i2;
    }
    __syncthreads();
    float av[16][2];
    #pragma unroll 1
    for (int it = 0; it < 16; ++it){
        int pw = (wave << 4) + it;
        float a0 = sr[pw*129 + lane],      b0 = si[pw*129 + lane];
        float a1 = sr[pw*129 + lane + 64], b1 = si[pw*129 + lane + 64];
        dit128t(tw, a0, b0, a1, b1);
        av[it][0] = __uint_as_float(packsplit(sqrtf(a0*a0 + b0*b0)));
        av[it][1] = __uint_as_float(packsplit(sqrtf(a1*a1 + b1*b1)));
    }
    __syncthreads();
    #pragma unroll 1
    for (int it = 0; it < 16; ++it){
        int pw = (wave << 4) + it;
        sr[lane*129 + pw] = av[it][0];
        sr[(lane+64)*129 + pw] = av[it][1];
    }
    __syncthreads();
    int row = threadIdx.x >> 2, cb = (threadIdx.x & 3) << 5;
    size_t ob = rb + ((size_t)row << 7) + cb;
    const float* s = &sr[row*129 + cb];
    #pragma unroll
    for (int q = 0; q < 8; ++q)
        *(float4*)(io + ob + (q << 2)) = make_float4(s[q*4], s[q*4+1], s[q*4+2], s[q*4+3]);
}

// ---------- K6: gating, IN-PLACE, 4-way split for occupancy ----------
__global__ __launch_bounds__(256) void k_gate(float* xre, float* xim,
                                              const float* __restrict__ w1, const float* __restrict__ b1,
                                              const float* __restrict__ bg, const float* __restrict__ bb_,
                                              const float* __restrict__ bm, const float* __restrict__ bv,
                                              const float* __restrict__ w2, const float* __restrict__ b2){
    __shared__ float w1T[256*17];
    __shared__ float w2s[256*16];
    __shared__ float yred[256*17];
    int t = threadIdx.x, g = t >> 6, col = t & 63;
    #pragma unroll
    for (int i = 0; i < 16; ++i) w1T[t*17 + i] = w1[i*256 + t];
    {
        const float4* s4 = (const float4*)w2; float4* d4 = (float4*)w2s;
        #pragma unroll
        for (int i = 0; i < 4; ++i) d4[i*256 + t] = s4[i*256 + t];
    }
    __syncthreads();
    int b = blockIdx.x >> 8;
    int n = ((blockIdx.x & 255) << 6) + col;
    size_t base = ((size_t)b << 8) * NFFT + n;
    float y[16];
    #pragma unroll
    for (int r = 0; r < 16; ++r) y[r] = 0.f;
    for (int c = g << 6; c < (g << 6) + 64; ++c){
        float xr = xre[base + (size_t)c*NFFT];
        #pragma unroll
        for (int r = 0; r < 16; ++r) y[r] += w1T[c*17 + r] * xr;
    }
    #pragma unroll
    for (int r = 0; r < 16; ++r) yred[t*17 + r] = y[r];
    __syncthreads();
    #pragma unroll
    for (int r = 0; r < 16; ++r){
        float v = yred[col*17 + r] + yred[(col+64)*17 + r]
                + yred[(col+128)*17 + r] + yred[(col+192)*17 + r] + b1[r];
        v = (v - bm[r]) * rsqrtf(bv[r] + 1e-5f) * bg[r] + bb_[r];
        y[r] = fmaxf(v, 0.f);
    }
    for (int o = g << 6; o < (g << 6) + 64; ++o){
        float s = b2[o];
        #pragma unroll
        for (int r = 0; r < 16; ++r) s += w2s[o*16 + r] * y[r];
        float gg = 1.f / (1.f + __expf(-s)) * 6.103515625e-05f;   // sigmoid * 1/16384
        float xr = xre[base + (size_t)o*NFFT];
        float xi = xim[base + (size_t)o*NFFT];
        xre[base + (size_t)o*NFFT] = gg * xr;
        xim[base + (size_t)o*NFFT] = gg * xi;
    }
}

// ---------- K7: fused ifft2 per image + abs -> PACKED bf16(hi|lo) into re plane ----------
__global__ __launch_bounds__(512) void k_ifft2_gate(float* re_io, const float* im_){
    __shared__ float sr[128*129], si[128*129];
    int lane = threadIdx.x & 63, wave = threadIdx.x >> 6;
    size_t ib = (size_t)blockIdx.x * NFFT;
    Tw tw; make_tw(tw);
    #pragma unroll 1
    for (int it = 0; it < 16; ++it){
        int jw = (wave << 4) + it;
        size_t base = ib + ((size_t)jw << 7);
        float a0 = re_io[base + lane], b0 = im_[base + lane];
        float a1 = re_io[base + lane + 64], b1 = im_[base + lane + 64];
        dit128t(tw, a0, b0, a1, b1);
        sr[lane*129 + jw] = a0;        si[lane*129 + jw] = b0;
        sr[(lane+64)*129 + jw] = a1;   si[(lane+64)*129 + jw] = b1;
    }
    __syncthreads();
    #pragma unroll 1
    for (int it = 0; it < 16; ++it){
        int ph = (wave << 4) + it;
        float a0 = sr[ph*129 + lane],      b0 = si[ph*129 + lane];
        float a1 = sr[ph*129 + lane + 64], b1 = si[ph*129 + lane + 64];
        dit128t(tw, a0, b0, a1, b1);
        size_t o = ib + ((size_t)ph << 7);
        re_io[o + lane]      = __uint_as_float(packsplit(sqrtf(a0*a0 + b0*b0)));
        re_io[o + lane + 64] = __uint_as_float(packsplit(sqrtf(a1*a1 + b1*b1)));
    }
}

// ---------- K7b: pack pw into (hi|lo) u32 ----------
__global__ __launch_bounds__(256) void k_pw_cvt(const float* __restrict__ pw, unsigned* __restrict__ pwp){
    int i = (blockIdx.x << 10) + (threadIdx.x << 2);
    float4 v = *(const float4*)(pw + i);
    uint4 o;
    o.x = packsplit(v.x); o.y = packsplit(v.y); o.z = packsplit(v.z); o.w = packsplit(v.w);
    *(uint4*)(pwp + i) = o;
}

// ---------- K8: projection via bf16 MFMA, pre-packed inputs ----------
// out[b][o][n] = sum_{q<512} pw[o][q] * cat[b][q][n]; M=256, K=512, N=65536
union FU { bf16x8 v; unsigned u[4]; };

__global__ __launch_bounds__(256) void k_proj(const unsigned* __restrict__ cat0, const unsigned* __restrict__ cat1,
                                              const unsigned* __restrict__ pwp, float* __restrict__ out){
    __shared__ unsigned As[128*33];   // [o][k] packed, stride 33
    __shared__ unsigned Bs[32*129];   // [k][n] packed, stride 129
    int t = threadIdx.x, lane = t & 63, wave = t >> 6;
    int quad = lane >> 4, l15 = lane & 15;
    int b  = blockIdx.x >> 8;
    int mo = (blockIdx.x >> 7) & 1;
    int nt = blockIdx.x & 127;
    int n0 = nt << 7;
    int wr = (wave >> 1) << 6;
    int wc = (wave & 1) << 6;

    f32x4 acc[4][4];
    #pragma unroll
    for (int i = 0; i < 4; ++i)
        #pragma unroll
        for (int j = 0; j < 4; ++j) acc[i][j] = (f32x4){0.f,0.f,0.f,0.f};

    int ao = t >> 1, ak = (t & 1) << 4;
    int bk = t >> 5, bn = t & 31;

    for (int ks = 0; ks < 16; ++ks){
        int k0 = ks << 5;
        __syncthreads();
        {
            const unsigned* ap = pwp + (size_t)((mo << 7) + ao)*512 + k0 + ak;
            #pragma unroll
            for (int i = 0; i < 16; ++i) As[ao*33 + ak + i] = ap[i];
        }
        {
            #pragma unroll
            for (int p = 0; p < 4; ++p){
                int q = k0 + (p << 3) + bk;
                const unsigned* srow = (q < 256) ? (cat0 + (size_t)((b<<8) + q) * NFFT)
                                                 : (cat1 + (size_t)((b<<8) + (q-256)) * NFFT);
                #pragma unroll
                for (int i = 0; i < 4; ++i){
                    int n = bn + (i << 5);
                    Bs[((p<<3) + bk)*129 + n] = srow[n0 + n];
                }
            }
        }
        __syncthreads();
        FU Ah[4], Al[4], Bh[4], Bl[4];
        #pragma unroll
        for (int mi = 0; mi < 4; ++mi){
            const unsigned* ap = &As[(wr + (mi << 4) + l15)*33 + (quad << 3)];
            #pragma unroll
            for (int p = 0; p < 4; ++p){
                unsigned e0 = ap[2*p], e1 = ap[2*p+1];
                Ah[mi].u[p] = (e0 >> 16) | (e1 & 0xFFFF0000u);
                Al[mi].u[p] = (e0 & 0xFFFFu) | (e1 << 16);
            }
        }
        #pragma unroll
        for (int ni = 0; ni < 4; ++ni){
            int n = wc + (ni << 4) + l15;
            #pragma unroll
            for (int p = 0; p < 4; ++p){
                unsigned e0 = Bs[((quad << 3) + 2*p)*129 + n];
                unsigned e1 = Bs[((quad << 3) + 2*p + 1)*129 + n];
                Bh[ni].u[p] = (e0 >> 16) | (e1 & 0xFFFF0000u);
                Bl[ni].u[p] = (e0 & 0xFFFFu) | (e1 << 16);
            }
        }
        #pragma unroll
        for (int mi = 0; mi < 4; ++mi)
            #pragma unroll
            for (int ni = 0; ni < 4; ++ni){
                acc[mi][ni] = __builtin_amdgcn_mfma_f32_16x16x32_bf16(Ah[mi].v, Bh[ni].v, acc[mi][ni], 0, 0, 0);
                acc[mi][ni] = __builtin_amdgcn_mfma_f32_16x16x32_bf16(Ah[mi].v, Bl[ni].v, acc[mi][ni], 0, 0, 0);
                acc[mi][ni] = __builtin_amdgcn_mfma_f32_16x16x32_bf16(Al[mi].v, Bh[ni].v, acc[mi][ni], 0, 0, 0);
            }
    }
    size_t obase = (size_t)((b << 8) + (mo << 7));
    #pragma unroll
    for (int mi = 0; mi < 4; ++mi)
        #pragma unroll
        for (int ni = 0; ni < 4; ++ni){
            int o_ = wr + (mi << 4) + (quad << 2);
            int n_ = n0 + wc + (ni << 4) + l15;
            float* op = out + (obase + o_)*NFFT + n_;
            #pragma unroll
            for (int r = 0; r < 4; ++r) op[(size_t)r*NFFT] = acc[mi][ni][r];
        }
}

// ---------- host ----------
extern "C" void kernel_launch(void* const* d_in, const int* in_sizes, int n_in,
                              void* d_out, int out_size, void* d_ws, size_t ws_size,
                              hipStream_t stream) {
    const float* x    = (const float*)d_in[0];
    const float* temp = (const float*)d_in[1];
    const float* w1   = (const float*)d_in[2];
    const float* b1   = (const float*)d_in[3];
    const float* bg   = (const float*)d_in[4];
    const float* bb_  = (const float*)d_in[5];
    const float* bm   = (const float*)d_in[6];
    const float* bv   = (const float*)d_in[7];
    const float* w2   = (const float*)d_in[8];
    const float* b2   = (const float*)d_in[9];
    const float* pw   = (const float*)d_in[10];
    float* out = (float*)d_out;

    float* ws = (float*)d_ws;
    float* Are  = ws;            // spectrum re -> gated in-place -> cat1 (packed)
    float* Aim  = ws + NP;       // spectrum im
    float* Ecat = ws + 2*NP;     // Gpart scratch -> mix im -> cat0 (packed, in-place)
    float* norm2 = ws + 3*NP;                  // 1024
    float* G     = norm2 + 1024;               // 65536
    float* attn2 = G + 65536;                  // 65536
    unsigned* pwpack = (unsigned*)(attn2 + 65536);  // 131072
    float* mixre = out;                        // d_out doubles as mix-re scratch
    float* Gpart = Ecat;                       // 8.4M floats, dead until k_mix

    size_t need = (3*NP + 1024 + 65536 + 65536 + 131072) * sizeof(float);
    if (ws_size < need) return;

    k_pw_cvt<<<128, 256, 0, stream>>>(pw, pwpack);
    k_fft2_fwd<<<1024, 512, 0, stream>>>(x, Are, Aim, norm2);
    k_gram<<<1024, 256, 0, stream>>>(Are, Aim, Gpart);
    k_gram_red<<<256, 256, 0, stream>>>(Gpart, G);
    k_attn<<<32, 256, 0, stream>>>(G, norm2, temp, attn2);
    k_mix<<<1024, 256, 0, stream>>>(Are, Aim, attn2, mixre, Ecat);
    k_ifft_n<<<1024, 512, 0, stream>>>(mixre, Ecat);
    k_gate<<<1024, 256, 0, stream>>>(Are, Aim, w1, b1, bg, bb_, bm, bv, w2, b2);
    k_ifft2_gate<<<1024, 512, 0, stream>>>(Are, Aim);
    k_proj<<<1024, 256, 0, stream>>>((const unsigned*)Ecat, (const unsigned*)Are, pwpack, out);
    (void)in_sizes; (void)n_in; (void)out_size; (void)ws_size;
}

// Round 7
// 765.080 us; speedup vs baseline: 1.3377x; 1.0813x over previous
//
#include <hip/hip_runtime.h>
#include <math.h>

// Problem constants: b=4, c=256, heads=8, c/head=32, h=w=128, n=16384, cr=16
#define NFFT 16384
static constexpr size_t NP = 16777216; // one plane = 1024 * 16384 floats

typedef short bf16x8 __attribute__((ext_vector_type(8)));
typedef float f32x4  __attribute__((ext_vector_type(4)));

// ---------- helpers ----------
__device__ __forceinline__ void sincos_rev(float rv, float& sn, float& cs){
    sn = __builtin_amdgcn_sinf(rv);   // sin(2*pi*rv)
    cs = __builtin_amdgcn_cosf(rv);
}
__device__ __forceinline__ int rev7(int v){ return (int)(__brev((unsigned)v) >> 25); }

__device__ __forceinline__ unsigned f2bf(float f){
    unsigned u = __float_as_uint(f);
    return (u + 0x7FFFu + ((u >> 16) & 1u)) >> 16;   // round-to-nearest-even
}
__device__ __forceinline__ float bf2f(unsigned h){ return __uint_as_float(h << 16); }
// pack fp32 -> (bf16 hi | bf16 lo) in one u32, stored via float bit-pattern
__device__ __forceinline__ unsigned packsplit(float v){
    unsigned h = f2bf(v);
    float r = v - bf2f(h);
    unsigned l = f2bf(r);
    return (h << 16) | l;
}

// Per-lane FFT twiddles, hoisted.
struct Tw { float c[7], s[7]; };
__device__ __forceinline__ void make_tw(Tw& t){
    const int l = threadIdx.x & 63;
    #pragma unroll
    for (int lg = 0; lg < 6; ++lg){
        int m = 1 << lg;
        int e = (l & (m-1)) * (64 >> lg);
        sincos_rev((float)e * 0.0078125f, t.s[lg], t.c[lg]);
    }
    sincos_rev((float)l * 0.0078125f, t.s[6], t.c[6]);
}

// DIF forward: natural in, slot j holds X[rev7(j)] out. W = e^{-2pi i/128}
__device__ __forceinline__ void dif128t(const Tw& t, float& r0, float& i0, float& r1, float& i1){
    const int l = threadIdx.x & 63;
    {   float cs = t.c[6], sn = -t.s[6];
        float ar = r0 + r1, ai = i0 + i1;
        float br = r0 - r1, bi = i0 - i1;
        r0 = ar; i0 = ai;
        r1 = br*cs - bi*sn; i1 = br*sn + bi*cs;
    }
    #pragma unroll
    for (int lg = 5; lg >= 0; --lg){
        int m = 1 << lg;
        float cs = t.c[lg], sn = -t.s[lg];
        bool up = (l & m) != 0;
        float pr = __shfl_xor(r0, m, 64), pi = __shfl_xor(i0, m, 64);
        float tr = up ? (pr - r0) : (r0 + pr);
        float ti = up ? (pi - i0) : (i0 + pi);
        r0 = up ? (tr*cs - ti*sn) : tr;
        i0 = up ? (tr*sn + ti*cs) : ti;
        pr = __shfl_xor(r1, m, 64); pi = __shfl_xor(i1, m, 64);
        tr = up ? (pr - r1) : (r1 + pr);
        ti = up ? (pi - i1) : (i1 + pi);
        r1 = up ? (tr*cs - ti*sn) : tr;
        i1 = up ? (tr*sn + ti*cs) : ti;
    }
}

// DIT inverse (unnormalized): slot j holds X[rev7(j)] in, natural out. W = e^{+2pi i/128}
__device__ __forceinline__ void dit128t(const Tw& t, float& r0, float& i0, float& r1, float& i1){
    const int l = threadIdx.x & 63;
    #pragma unroll
    for (int lg = 0; lg <= 5; ++lg){
        int m = 1 << lg;
        float cs = t.c[lg], sn = t.s[lg];
        bool up = (l & m) != 0;
        float pr = __shfl_xor(r0, m, 64), pi = __shfl_xor(i0, m, 64);
        float vr = up ? r0 : pr, vi = up ? i0 : pi;
        float wr = vr*cs - vi*sn, wi = vr*sn + vi*cs;
        r0 = up ? (pr - wr) : (r0 + wr);
        i0 = up ? (pi - wi) : (i0 + wi);
        pr = __shfl_xor(r1, m, 64); pi = __shfl_xor(i1, m, 64);
        vr = up ? r1 : pr; vi = up ? i1 : pi;
        wr = vr*cs - vi*sn; wi = vr*sn + vi*cs;
        r1 = up ? (pr - wr) : (r1 + wr);
        i1 = up ? (pi - wi) : (i1 + wi);
    }
    {   float cs = t.c[6], sn = t.s[6];
        float wr = r1*cs - i1*sn, wi = r1*sn + i1*cs;
        float ar = r0 + wr, ai = i0 + wi;
        r1 = r0 - wr; i1 = i0 - wi;
        r0 = ar; i0 = ai;
    }
}

// ---------- K1: fused forward fft2 per image, 1024 threads (16 waves, 4/SIMD) ----------
__global__ __launch_bounds__(1024) void k_fft2_fwd(const float* __restrict__ x,
                                                   float* __restrict__ ore, float* __restrict__ oim,
                                                   float* __restrict__ norm2){
    __shared__ float sr[128*129], si[128*129];
    __shared__ float red[16];
    int lane = threadIdx.x & 63, wave = threadIdx.x >> 6;
    int img = blockIdx.x;
    Tw tw; make_tw(tw);
    const float* base = x + (size_t)img * NFFT;
    #pragma unroll 1
    for (int it = 0; it < 8; ++it){
        int h = (wave << 3) + it;
        float a0 = base[h*128 + lane], b0 = 0.f;
        float a1 = base[h*128 + lane + 64], b1 = 0.f;
        dif128t(tw, a0, b0, a1, b1);
        sr[lane*129 + h] = a0;        si[lane*129 + h] = b0;
        sr[(lane+64)*129 + h] = a1;   si[(lane+64)*129 + h] = b1;
    }
    __syncthreads();
    float acc = 0.f;
    #pragma unroll 1
    for (int it = 0; it < 8; ++it){
        int j = (wave << 3) + it;
        float a0 = sr[j*129 + lane],      b0 = si[j*129 + lane];
        float a1 = sr[j*129 + lane + 64], b1 = si[j*129 + lane + 64];
        dif128t(tw, a0, b0, a1, b1);
        size_t o = (size_t)img*NFFT + (size_t)j*128;
        ore[o + lane] = a0;      oim[o + lane] = b0;
        ore[o + lane + 64] = a1; oim[o + lane + 64] = b1;
        acc += a0*a0 + b0*b0 + a1*a1 + b1*b1;
    }
    #pragma unroll
    for (int m = 32; m >= 1; m >>= 1) acc += __shfl_xor(acc, m, 64);
    if (lane == 0) red[wave] = acc;
    __syncthreads();
    if (threadIdx.x == 0){
        float s = 0.f;
        #pragma unroll
        for (int i = 0; i < 16; ++i) s += red[i];
        norm2[img] = s;
    }
}

// ---------- K2: gram partials, atomic-free ----------
__global__ __launch_bounds__(256) void k_gram(const float* __restrict__ xre, const float* __restrict__ xim,
                                              float* __restrict__ Gpart){
    __shared__ float lr[64*36], li[64*36];
    int t = threadIdx.x, lane = t & 63, wave = t >> 6;
    int bh = blockIdx.x >> 5;
    int n0 = (blockIdx.x & 31) << 9;
    size_t cbase = (size_t)bh * 32 * NFFT;
    int c0 = (lane >> 3) << 2, d0 = (lane & 7) << 2;
    float are[16], aim[16];
    #pragma unroll
    for (int i = 0; i < 16; ++i){ are[i] = 0.f; aim[i] = 0.f; }
    for (int nt = 0; nt < 8; ++nt){
        int nb = n0 + (nt << 6);
        __syncthreads();
        #pragma unroll
        for (int r = 0; r < 8; ++r){
            int ch = (wave << 3) + r;
            lr[lane*36 + ch] = xre[cbase + (size_t)ch*NFFT + nb + lane];
            li[lane*36 + ch] = xim[cbase + (size_t)ch*NFFT + nb + lane];
        }
        __syncthreads();
        for (int j = (wave<<4); j < (wave<<4) + 16; ++j){
            float4 xr = *(const float4*)&lr[j*36 + c0];
            float4 xi = *(const float4*)&li[j*36 + c0];
            float4 yr = *(const float4*)&lr[j*36 + d0];
            float4 yi = *(const float4*)&li[j*36 + d0];
            const float xrv[4] = {xr.x, xr.y, xr.z, xr.w};
            const float xiv[4] = {xi.x, xi.y, xi.z, xi.w};
            const float yrv[4] = {yr.x, yr.y, yr.z, yr.w};
            const float yiv[4] = {yi.x, yi.y, yi.z, yi.w};
            #pragma unroll
            for (int ci = 0; ci < 4; ++ci)
                #pragma unroll
                for (int di = 0; di < 4; ++di){
                    are[ci*4+di] += xrv[ci]*yrv[di] - xiv[ci]*yiv[di];
                    aim[ci*4+di] += xrv[ci]*yiv[di] + xiv[ci]*yrv[di];
                }
        }
    }
    float* gp = Gpart + ((size_t)blockIdx.x * 4 + wave) * 2048;
    #pragma unroll
    for (int ci = 0; ci < 4; ++ci)
        #pragma unroll
        for (int di = 0; di < 4; ++di){
            int idx = ((c0+ci)*32 + d0+di) * 2;
            gp[idx]     = are[ci*4+di];
            gp[idx + 1] = aim[ci*4+di];
        }
}

// ---------- K2b: reduce 128 partials per bh ----------
__global__ __launch_bounds__(256) void k_gram_red(const float* __restrict__ Gpart, float* __restrict__ G){
    int bh = blockIdx.x >> 3;
    int q  = ((blockIdx.x & 7) << 8) + threadIdx.x;
    const float* gp = Gpart + (size_t)bh * 128 * 2048 + q;
    float s = 0.f;
    #pragma unroll 8
    for (int p = 0; p < 128; ++p) s += gp[(size_t)p * 2048];
    G[(size_t)bh * 2048 + q] = s;
}

// ---------- K3: normalize, temperature, complex softmax, fold IF32 * (1/524288) ----------
__global__ __launch_bounds__(256) void k_attn(const float* __restrict__ G, const float* __restrict__ norm2,
                                              const float* __restrict__ temp, float* __restrict__ attn2){
    __shared__ float ar[32*33], ai[32*33];
    int bh = blockIdx.x, h = bh & 7, t = threadIdx.x;
    if (t < 32){
        float tv = temp[h];
        float nc = fmaxf(sqrtf(norm2[(bh<<5) + t]), 1e-12f);
        const float* gr = G + (size_t)bh*2048 + t*64;
        float mr = -1e30f, mi = -1e30f;
        for (int d = 0; d < 32; ++d){
            float nd = fmaxf(sqrtf(norm2[(bh<<5) + d]), 1e-12f);
            float s = tv / (nc * nd);
            float vr = gr[d*2] * s, vi = gr[d*2+1] * s;
            ar[t*33+d] = vr; ai[t*33+d] = vi;
            mr = fmaxf(mr, vr); mi = fmaxf(mi, vi);
        }
        float sr = 0.f, si = 0.f;
        for (int d = 0; d < 32; ++d){
            float er = __expf(ar[t*33+d] - mr), ei = __expf(ai[t*33+d] - mi);
            ar[t*33+d] = er; ai[t*33+d] = ei; sr += er; si += ei;
        }
        sr = 1.f/sr; si = 1.f/si;
        for (int d = 0; d < 32; ++d){ ar[t*33+d] *= sr; ai[t*33+d] *= si; }
    }
    __syncthreads();
    const float S = 1.f / 524288.f;
    for (int q = t; q < 1024; q += 256){
        int e = q >> 5, d = q & 31;
        float sr = 0.f, si = 0.f;
        for (int c = 0; c < 32; ++c){
            float sn, cs; sincos_rev((float)((e*c) & 31) * 0.03125f, sn, cs);
            float xr = ar[c*33+d], xi = ai[c*33+d];
            sr += cs*xr - sn*xi;
            si += cs*xi + sn*xr;
        }
        attn2[(size_t)bh*2048 + q*2]     = sr * S;
        attn2[(size_t)bh*2048 + q*2 + 1] = si * S;
    }
}

// ---------- K4: mix[e][n] = sum_d attn2[e][d] * X[d][n]  (complex) ----------
__global__ __launch_bounds__(256) void k_mix(const float* __restrict__ xre, const float* __restrict__ xim,
                                             const float* __restrict__ attn2,
                                             float* __restrict__ ore, float* __restrict__ oim){
    __shared__ float a2[2048];
    __shared__ float lr[32*65], li[32*65];
    int t = threadIdx.x, lane = t & 63, wave = t >> 6;
    int bh = blockIdx.x >> 5;
    int n0 = (blockIdx.x & 31) << 9;
    size_t cbase = (size_t)bh * 32 * NFFT;
    {
        const float4* s4 = (const float4*)(attn2 + (size_t)bh*2048);
        float4* d4 = (float4*)a2;
        d4[t] = s4[t]; d4[t + 256] = s4[t + 256];
    }
    for (int tile = 0; tile < 8; ++tile){
        int nb = n0 + (tile << 6);
        __syncthreads();
        #pragma unroll
        for (int r = 0; r < 8; ++r){
            int ch = (wave << 3) + r;
            lr[ch*65 + lane] = xre[cbase + (size_t)ch*NFFT + nb + lane];
            li[ch*65 + lane] = xim[cbase + (size_t)ch*NFFT + nb + lane];
        }
        __syncthreads();
        float accr[8] = {0,0,0,0,0,0,0,0}, acci[8] = {0,0,0,0,0,0,0,0};
        for (int d = 0; d < 32; d += 2){
            float xr0 = lr[d*65 + lane],     xi0 = li[d*65 + lane];
            float xr1 = lr[(d+1)*65 + lane], xi1 = li[(d+1)*65 + lane];
            #pragma unroll
            for (int k = 0; k < 8; ++k){
                int e = (wave << 3) + k;
                const float4 w = *(const float4*)&a2[(e << 6) + (d << 1)];
                accr[k] += w.x*xr0 - w.y*xi0 + w.z*xr1 - w.w*xi1;
                acci[k] += w.x*xi0 + w.y*xr0 + w.z*xi1 + w.w*xr1;
            }
        }
        #pragma unroll
        for (int k = 0; k < 8; ++k){
            int e = (wave << 3) + k;
            ore[cbase + (size_t)e*NFFT + nb + lane] = accr[k];
            oim[cbase + (size_t)e*NFFT + nb + lane] = acci[k];
        }
    }
}

// ---------- K5: fused 16384-pt inverse FFT + abs per row, 1024 threads; PACKED bf16(hi|lo) into io ----------
__global__ __launch_bounds__(1024) void k_ifft_n(const float* ire, float* io){
    __shared__ float sr[128*129], si[128*129];
    int lane = threadIdx.x & 63, wave = threadIdx.x >> 6;
    size_t rb = (size_t)blockIdx.x * NFFT;
    Tw tw; make_tw(tw);
    #pragma unroll 1
    for (int it = 0; it < 8; ++it){
        int jw = (wave << 3) + it;
        size_t base = rb + ((size_t)jw << 7);
        float a0 = ire[base + lane], b0 = io[base + lane];
        float a1 = ire[base + lane + 64], b1 = io[base + lane + 64];
        dit128t(tw, a0, b0, a1, b1);
        int kw = rev7(jw);
        float sn, cs;
        sincos_rev((float)(lane * kw) * 6.103515625e-05f, sn, cs);
        float r = a0*cs - b0*sn, i2 = a0*sn + b0*cs;
        sr[lane*129 + jw] = r; si[lane*129 + jw] = i2;
        sincos_rev((float)((lane + 64) * kw) * 6.103515625e-05f, sn, cs);
        r = a1*cs - b1*sn; i2 = a1*sn + b1*cs;
        sr[(lane+64)*129 + jw] = r; si[(lane+64)*129 + jw] = i2;
    }
    __syncthreads();
    float av[8][2];
    #pragma unroll 1
    for (int it = 0; it < 8; ++it){
        int pw = (wave << 3) + it;
        float a0 = sr[pw*129 + lane],      b0 = si[pw*129 + lane];
        float a1 = sr[pw*129 + lane + 64], b1 = si[pw*129 + lane + 64];
        dit128t(tw, a0, b0, a1, b1);
        av[it][0] = __uint_as_float(packsplit(sqrtf(a0*a0 + b0*b0)));
        av[it][1] = __uint_as_float(packsplit(sqrtf(a1*a1 + b1*b1)));
    }
    __syncthreads();
    #pragma unroll 1
    for (int it = 0; it < 8; ++it){
        int pw = (wave << 3) + it;
        sr[lane*129 + pw] = av[it][0];
        sr[(lane+64)*129 + pw] = av[it][1];
    }
    __syncthreads();
    int row = threadIdx.x >> 3, cb = (threadIdx.x & 7) << 4;
    size_t ob = rb + ((size_t)row << 7) + cb;
    const float* s = &sr[row*129 + cb];
    #pragma unroll
    for (int q = 0; q < 4; ++q)
        *(float4*)(io + ob + (q << 2)) = make_float4(s[q*4], s[q*4+1], s[q*4+2], s[q*4+3]);
}

// ---------- K6: gating, IN-PLACE, 4-way split for occupancy ----------
__global__ __launch_bounds__(256) void k_gate(float* xre, float* xim,
                                              const float* __restrict__ w1, const float* __restrict__ b1,
                                              const float* __restrict__ bg, const float* __restrict__ bb_,
                                              const float* __restrict__ bm, const float* __restrict__ bv,
                                              const float* __restrict__ w2, const float* __restrict__ b2){
    __shared__ float w1T[256*17];
    __shared__ float w2s[256*16];
    __shared__ float yred[256*17];
    int t = threadIdx.x, g = t >> 6, col = t & 63;
    #pragma unroll
    for (int i = 0; i < 16; ++i) w1T[t*17 + i] = w1[i*256 + t];
    {
        const float4* s4 = (const float4*)w2; float4* d4 = (float4*)w2s;
        #pragma unroll
        for (int i = 0; i < 4; ++i) d4[i*256 + t] = s4[i*256 + t];
    }
    __syncthreads();
    int b = blockIdx.x >> 8;
    int n = ((blockIdx.x & 255) << 6) + col;
    size_t base = ((size_t)b << 8) * NFFT + n;
    float y[16];
    #pragma unroll
    for (int r = 0; r < 16; ++r) y[r] = 0.f;
    for (int c = g << 6; c < (g << 6) + 64; ++c){
        float xr = xre[base + (size_t)c*NFFT];
        #pragma unroll
        for (int r = 0; r < 16; ++r) y[r] += w1T[c*17 + r] * xr;
    }
    #pragma unroll
    for (int r = 0; r < 16; ++r) yred[t*17 + r] = y[r];
    __syncthreads();
    #pragma unroll
    for (int r = 0; r < 16; ++r){
        float v = yred[col*17 + r] + yred[(col+64)*17 + r]
                + yred[(col+128)*17 + r] + yred[(col+192)*17 + r] + b1[r];
        v = (v - bm[r]) * rsqrtf(bv[r] + 1e-5f) * bg[r] + bb_[r];
        y[r] = fmaxf(v, 0.f);
    }
    for (int o = g << 6; o < (g << 6) + 64; ++o){
        float s = b2[o];
        #pragma unroll
        for (int r = 0; r < 16; ++r) s += w2s[o*16 + r] * y[r];
        float gg = 1.f / (1.f + __expf(-s)) * 6.103515625e-05f;   // sigmoid * 1/16384
        float xr = xre[base + (size_t)o*NFFT];
        float xi = xim[base + (size_t)o*NFFT];
        xre[base + (size_t)o*NFFT] = gg * xr;
        xim[base + (size_t)o*NFFT] = gg * xi;
    }
}

// ---------- K7: fused ifft2 per image + abs, 1024 threads -> PACKED bf16(hi|lo) into re plane ----------
__global__ __launch_bounds__(1024) void k_ifft2_gate(float* re_io, const float* im_){
    __shared__ float sr[128*129], si[128*129];
    int lane = threadIdx.x & 63, wave = threadIdx.x >> 6;
    size_t ib = (size_t)blockIdx.x * NFFT;
    Tw tw; make_tw(tw);
    #pragma unroll 1
    for (int it = 0; it < 8; ++it){
        int jw = (wave << 3) + it;
        size_t base = ib + ((size_t)jw << 7);
        float a0 = re_io[base + lane], b0 = im_[base + lane];
        float a1 = re_io[base + lane + 64], b1 = im_[base + lane + 64];
        dit128t(tw, a0, b0, a1, b1);
        sr[lane*129 + jw] = a0;        si[lane*129 + jw] = b0;
        sr[(lane+64)*129 + jw] = a1;   si[(lane+64)*129 + jw] = b1;
    }
    __syncthreads();
    #pragma unroll 1
    for (int it = 0; it < 8; ++it){
        int ph = (wave << 3) + it;
        float a0 = sr[ph*129 + lane],      b0 = si[ph*129 + lane];
        float a1 = sr[ph*129 + lane + 64], b1 = si[ph*129 + lane + 64];
        dit128t(tw, a0, b0, a1, b1);
        size_t o = ib + ((size_t)ph << 7);
        re_io[o + lane]      = __uint_as_float(packsplit(sqrtf(a0*a0 + b0*b0)));
        re_io[o + lane + 64] = __uint_as_float(packsplit(sqrtf(a1*a1 + b1*b1)));
    }
}

// ---------- K7b: pack pw into (hi|lo) u32 ----------
__global__ __launch_bounds__(256) void k_pw_cvt(const float* __restrict__ pw, unsigned* __restrict__ pwp){
    int i = (blockIdx.x << 10) + (threadIdx.x << 2);
    float4 v = *(const float4*)(pw + i);
    uint4 o;
    o.x = packsplit(v.x); o.y = packsplit(v.y); o.z = packsplit(v.z); o.w = packsplit(v.w);
    *(uint4*)(pwp + i) = o;
}

// ---------- K8: projection via bf16 MFMA, pre-packed inputs ----------
union FU { bf16x8 v; unsigned u[4]; };

__global__ __launch_bounds__(256) void k_proj(const unsigned* __restrict__ cat0, const unsigned* __restrict__ cat1,
                                              const unsigned* __restrict__ pwp, float* __restrict__ out){
    __shared__ unsigned As[128*33];   // [o][k] packed, stride 33
    __shared__ unsigned Bs[32*129];   // [k][n] packed, stride 129
    int t = threadIdx.x, lane = t & 63, wave = t >> 6;
    int quad = lane >> 4, l15 = lane & 15;
    int b  = blockIdx.x >> 8;
    int mo = (blockIdx.x >> 7) & 1;
    int nt = blockIdx.x & 127;
    int n0 = nt << 7;
    int wr = (wave >> 1) << 6;
    int wc = (wave & 1) << 6;

    f32x4 acc[4][4];
    #pragma unroll
    for (int i = 0; i < 4; ++i)
        #pragma unroll
        for (int j = 0; j < 4; ++j) acc[i][j] = (f32x4){0.f,0.f,0.f,0.f};

    int ao = t >> 1, ak = (t & 1) << 4;
    int bk = t >> 5, bn = t & 31;

    for (int ks = 0; ks < 16; ++ks){
        int k0 = ks << 5;
        __syncthreads();
        {
            const unsigned* ap = pwp + (size_t)((mo << 7) + ao)*512 + k0 + ak;
            #pragma unroll
            for (int i = 0; i < 16; ++i) As[ao*33 + ak + i] = ap[i];
        }
        {
            #pragma unroll
            for (int p = 0; p < 4; ++p){
                int q = k0 + (p << 3) + bk;
                const unsigned* srow = (q < 256) ? (cat0 + (size_t)((b<<8) + q) * NFFT)
                                                 : (cat1 + (size_t)((b<<8) + (q-256)) * NFFT);
                #pragma unroll
                for (int i = 0; i < 4; ++i){
                    int n = bn + (i << 5);
                    Bs[((p<<3) + bk)*129 + n] = srow[n0 + n];
                }
            }
        }
        __syncthreads();
        FU Ah[4], Al[4], Bh[4], Bl[4];
        #pragma unroll
        for (int mi = 0; mi < 4; ++mi){
            const unsigned* ap = &As[(wr + (mi << 4) + l15)*33 + (quad << 3)];
            #pragma unroll
            for (int p = 0; p < 4; ++p){
                unsigned e0 = ap[2*p], e1 = ap[2*p+1];
                Ah[mi].u[p] = (e0 >> 16) | (e1 & 0xFFFF0000u);
                Al[mi].u[p] = (e0 & 0xFFFFu) | (e1 << 16);
            }
        }
        #pragma unroll
        for (int ni = 0; ni < 4; ++ni){
            int n = wc + (ni << 4) + l15;
            #pragma unroll
            for (int p = 0; p < 4; ++p){
                unsigned e0 = Bs[((quad << 3) + 2*p)*129 + n];
                unsigned e1 = Bs[((quad << 3) + 2*p + 1)*129 + n];
                Bh[ni].u[p] = (e0 >> 16) | (e1 & 0xFFFF0000u);
                Bl[ni].u[p] = (e0 & 0xFFFFu) | (e1 << 16);
            }
        }
        #pragma unroll
        for (int mi = 0; mi < 4; ++mi)
            #pragma unroll
            for (int ni = 0; ni < 4; ++ni){
                acc[mi][ni] = __builtin_amdgcn_mfma_f32_16x16x32_bf16(Ah[mi].v, Bh[ni].v, acc[mi][ni], 0, 0, 0);
                acc[mi][ni] = __builtin_amdgcn_mfma_f32_16x16x32_bf16(Ah[mi].v, Bl[ni].v, acc[mi][ni], 0, 0, 0);
                acc[mi][ni] = __builtin_amdgcn_mfma_f32_16x16x32_bf16(Al[mi].v, Bh[ni].v, acc[mi][ni], 0, 0, 0);
            }
    }
    size_t obase = (size_t)((b << 8) + (mo << 7));
    #pragma unroll
    for (int mi = 0; mi < 4; ++mi)
        #pragma unroll
        for (int ni = 0; ni < 4; ++ni){
            int o_ = wr + (mi << 4) + (quad << 2);
            int n_ = n0 + wc + (ni << 4) + l15;
            float* op = out + (obase + o_)*NFFT + n_;
            #pragma unroll
            for (int r = 0; r < 4; ++r) op[(size_t)r*NFFT] = acc[mi][ni][r];
        }
}

// ---------- host ----------
extern "C" void kernel_launch(void* const* d_in, const int* in_sizes, int n_in,
                              void* d_out, int out_size, void* d_ws, size_t ws_size,
                              hipStream_t stream) {
    const float* x    = (const float*)d_in[0];
    const float* temp = (const float*)d_in[1];
    const float* w1   = (const float*)d_in[2];
    const float* b1   = (const float*)d_in[3];
    const float* bg   = (const float*)d_in[4];
    const float* bb_  = (const float*)d_in[5];
    const float* bm   = (const float*)d_in[6];
    const float* bv   = (const float*)d_in[7];
    const float* w2   = (const float*)d_in[8];
    const float* b2   = (const float*)d_in[9];
    const float* pw   = (const float*)d_in[10];
    float* out = (float*)d_out;

    float* ws = (float*)d_ws;
    float* Are  = ws;            // spectrum re -> gated in-place -> cat1 (packed)
    float* Aim  = ws + NP;       // spectrum im
    float* Ecat = ws + 2*NP;     // Gpart scratch -> mix im -> cat0 (packed, in-place)
    float* norm2 = ws + 3*NP;                  // 1024
    float* G     = norm2 + 1024;               // 65536
    float* attn2 = G + 65536;                  // 65536
    unsigned* pwpack = (unsigned*)(attn2 + 65536);  // 131072
    float* mixre = out;                        // d_out doubles as mix-re scratch
    float* Gpart = Ecat;                       // 8.4M floats, dead until k_mix

    size_t need = (3*NP + 1024 + 65536 + 65536 + 131072) * sizeof(float);
    if (ws_size < need) return;

    k_pw_cvt<<<128, 256, 0, stream>>>(pw, pwpack);
    k_fft2_fwd<<<1024, 1024, 0, stream>>>(x, Are, Aim, norm2);
    k_gram<<<1024, 256, 0, stream>>>(Are, Aim, Gpart);
    k_gram_red<<<256, 256, 0, stream>>>(Gpart, G);
    k_attn<<<32, 256, 0, stream>>>(G, norm2, temp, attn2);
    k_mix<<<1024, 256, 0, stream>>>(Are, Aim, attn2, mixre, Ecat);
    k_ifft_n<<<1024, 1024, 0, stream>>>(mixre, Ecat);
    k_gate<<<1024, 256, 0, stream>>>(Are, Aim, w1, b1, bg, bb_, bm, bv, w2, b2);
    k_ifft2_gate<<<1024, 1024, 0, stream>>>(Are, Aim);
    k_proj<<<1024, 256, 0, stream>>>((const unsigned*)Ecat, (const unsigned*)Are, pwpack, out);
    (void)in_sizes; (void)n_in; (void)out_size; (void)ws_size;
}

// Round 8
// 755.841 us; speedup vs baseline: 1.3541x; 1.0122x over previous
//
#include <hip/hip_runtime.h>
#include <math.h>

// Problem constants: b=4, c=256, heads=8, c/head=32, h=w=128, n=16384, cr=16
#define NFFT 16384
static constexpr size_t NP = 16777216; // one plane = 1024 * 16384 floats

typedef short bf16x8 __attribute__((ext_vector_type(8)));
typedef float f32x4  __attribute__((ext_vector_type(4)));

// ---------- helpers ----------
__device__ __forceinline__ void sincos_rev(float rv, float& sn, float& cs){
    sn = __builtin_amdgcn_sinf(rv);   // sin(2*pi*rv)
    cs = __builtin_amdgcn_cosf(rv);
}
__device__ __forceinline__ int rev7(int v){ return (int)(__brev((unsigned)v) >> 25); }

__device__ __forceinline__ unsigned f2bf(float f){
    unsigned u = __float_as_uint(f);
    return (u + 0x7FFFu + ((u >> 16) & 1u)) >> 16;   // round-to-nearest-even
}
__device__ __forceinline__ float bf2f(unsigned h){ return __uint_as_float(h << 16); }
// pack fp32 -> (bf16 hi | bf16 lo) in one u32, stored via float bit-pattern
__device__ __forceinline__ unsigned packsplit(float v){
    unsigned h = f2bf(v);
    float r = v - bf2f(h);
    unsigned l = f2bf(r);
    return (h << 16) | l;
}

// ---------- sign/identity-folded per-lane twiddles ----------
// DIF (forward): per stage, down-lane: w'=(1,0), sg=+1; up-lane: w'=(cos, -sin), sg=-1.
struct TwF { float cw[6], sw[6], sg[6], c6, s6; };
__device__ __forceinline__ void make_twf(TwF& t){
    const int l = threadIdx.x & 63;
    #pragma unroll
    for (int lg = 0; lg < 6; ++lg){
        int m = 1 << lg;
        bool up = (l & m) != 0;
        int e = (l & (m-1)) * (64 >> lg);
        float sn, cs; sincos_rev((float)e * 0.0078125f, sn, cs);
        t.cw[lg] = up ? cs : 1.f;
        t.sw[lg] = up ? -sn : 0.f;
        t.sg[lg] = up ? -1.f : 1.f;
    }
    sincos_rev((float)l * 0.0078125f, t.s6, t.c6);
}
// DIT (inverse): both lanes multiply by w=(cos,sin); up-lane sign-negated: w'=-w.
struct TwI { float cw[6], sw[6], c6, s6; };
__device__ __forceinline__ void make_twi(TwI& t){
    const int l = threadIdx.x & 63;
    #pragma unroll
    for (int lg = 0; lg < 6; ++lg){
        int m = 1 << lg;
        bool up = (l & m) != 0;
        int e = (l & (m-1)) * (64 >> lg);
        float sn, cs; sincos_rev((float)e * 0.0078125f, sn, cs);
        t.cw[lg] = up ? -cs : cs;
        t.sw[lg] = up ? -sn : sn;
    }
    sincos_rev((float)l * 0.0078125f, t.s6, t.c6);
}

// DIF forward: natural in, slot j holds X[rev7(j)] out. W = e^{-2pi i/128}
__device__ __forceinline__ void dif128t(const TwF& t, float& r0, float& i0, float& r1, float& i1){
    {   // span 64: (r0-r1) * W^l, W=e^{-2pi i/128}
        float ar = r0 + r1, ai = i0 + i1;
        float br = r0 - r1, bi = i0 - i1;
        r0 = ar; i0 = ai;
        r1 =  br*t.c6 + bi*t.s6;
        i1 = -br*t.s6 + bi*t.c6;
    }
    #pragma unroll
    for (int lg = 5; lg >= 0; --lg){
        int m = 1 << lg;
        float cw = t.cw[lg], sw = t.sw[lg], sg = t.sg[lg];
        float pr = __shfl_xor(r0, m, 64), pi = __shfl_xor(i0, m, 64);
        float tr = fmaf(sg, r0, pr), ti = fmaf(sg, i0, pi);
        r0 = tr*cw - ti*sw;
        i0 = tr*sw + ti*cw;
        pr = __shfl_xor(r1, m, 64); pi = __shfl_xor(i1, m, 64);
        tr = fmaf(sg, r1, pr); ti = fmaf(sg, i1, pi);
        r1 = tr*cw - ti*sw;
        i1 = tr*sw + ti*cw;
    }
}

// DIT inverse (unnormalized): slot j holds X[rev7(j)] in, natural out. W = e^{+2pi i/128}
__device__ __forceinline__ void dit128t(const TwI& t, float& r0, float& i0, float& r1, float& i1){
    const int l = threadIdx.x & 63;
    #pragma unroll
    for (int lg = 0; lg <= 5; ++lg){
        int m = 1 << lg;
        bool up = (l & m) != 0;
        float cw = t.cw[lg], sw = t.sw[lg];
        float pr = __shfl_xor(r0, m, 64), pi = __shfl_xor(i0, m, 64);
        float vr = up ? r0 : pr, vi = up ? i0 : pi;
        float ar = up ? pr : r0, ai = up ? pi : i0;
        r0 = fmaf(vr, cw, fmaf(vi, -sw, ar));
        i0 = fmaf(vr, sw, fmaf(vi,  cw, ai));
        pr = __shfl_xor(r1, m, 64); pi = __shfl_xor(i1, m, 64);
        vr = up ? r1 : pr; vi = up ? i1 : pi;
        ar = up ? pr : r1; ai = up ? pi : i1;
        r1 = fmaf(vr, cw, fmaf(vi, -sw, ar));
        i1 = fmaf(vr, sw, fmaf(vi,  cw, ai));
    }
    {   // span 64: w = e^{+2pi i l/128}
        float wr = r1*t.c6 - i1*t.s6, wi = r1*t.s6 + i1*t.c6;
        float ar = r0 + wr, ai = i0 + wi;
        r1 = r0 - wr; i1 = i0 - wi;
        r0 = ar; i0 = ai;
    }
}

// ---------- K1: fused forward fft2 per image, 1024 threads ----------
__global__ __launch_bounds__(1024) void k_fft2_fwd(const float* __restrict__ x,
                                                   float* __restrict__ ore, float* __restrict__ oim,
                                                   float* __restrict__ norm2){
    __shared__ float sr[128*129], si[128*129];
    __shared__ float red[16];
    int lane = threadIdx.x & 63, wave = threadIdx.x >> 6;
    int img = blockIdx.x;
    TwF tw; make_twf(tw);
    const float* base = x + (size_t)img * NFFT;
    #pragma unroll 2
    for (int it = 0; it < 8; ++it){
        int h = (wave << 3) + it;
        float a0 = base[h*128 + lane], b0 = 0.f;
        float a1 = base[h*128 + lane + 64], b1 = 0.f;
        dif128t(tw, a0, b0, a1, b1);
        sr[lane*129 + h] = a0;        si[lane*129 + h] = b0;
        sr[(lane+64)*129 + h] = a1;   si[(lane+64)*129 + h] = b1;
    }
    __syncthreads();
    float acc = 0.f;
    #pragma unroll 2
    for (int it = 0; it < 8; ++it){
        int j = (wave << 3) + it;
        float a0 = sr[j*129 + lane],      b0 = si[j*129 + lane];
        float a1 = sr[j*129 + lane + 64], b1 = si[j*129 + lane + 64];
        dif128t(tw, a0, b0, a1, b1);
        size_t o = (size_t)img*NFFT + (size_t)j*128;
        ore[o + lane] = a0;      oim[o + lane] = b0;
        ore[o + lane + 64] = a1; oim[o + lane + 64] = b1;
        acc += a0*a0 + b0*b0 + a1*a1 + b1*b1;
    }
    #pragma unroll
    for (int m = 32; m >= 1; m >>= 1) acc += __shfl_xor(acc, m, 64);
    if (lane == 0) red[wave] = acc;
    __syncthreads();
    if (threadIdx.x == 0){
        float s = 0.f;
        #pragma unroll
        for (int i = 0; i < 16; ++i) s += red[i];
        norm2[img] = s;
    }
}

// ---------- K2: gram partials, atomic-free ----------
__global__ __launch_bounds__(256) void k_gram(const float* __restrict__ xre, const float* __restrict__ xim,
                                              float* __restrict__ Gpart){
    __shared__ float lr[64*36], li[64*36];
    int t = threadIdx.x, lane = t & 63, wave = t >> 6;
    int bh = blockIdx.x >> 5;
    int n0 = (blockIdx.x & 31) << 9;
    size_t cbase = (size_t)bh * 32 * NFFT;
    int c0 = (lane >> 3) << 2, d0 = (lane & 7) << 2;
    float are[16], aim[16];
    #pragma unroll
    for (int i = 0; i < 16; ++i){ are[i] = 0.f; aim[i] = 0.f; }
    for (int nt = 0; nt < 8; ++nt){
        int nb = n0 + (nt << 6);
        __syncthreads();
        #pragma unroll
        for (int r = 0; r < 8; ++r){
            int ch = (wave << 3) + r;
            lr[lane*36 + ch] = xre[cbase + (size_t)ch*NFFT + nb + lane];
            li[lane*36 + ch] = xim[cbase + (size_t)ch*NFFT + nb + lane];
        }
        __syncthreads();
        for (int j = (wave<<4); j < (wave<<4) + 16; ++j){
            float4 xr = *(const float4*)&lr[j*36 + c0];
            float4 xi = *(const float4*)&li[j*36 + c0];
            float4 yr = *(const float4*)&lr[j*36 + d0];
            float4 yi = *(const float4*)&li[j*36 + d0];
            const float xrv[4] = {xr.x, xr.y, xr.z, xr.w};
            const float xiv[4] = {xi.x, xi.y, xi.z, xi.w};
            const float yrv[4] = {yr.x, yr.y, yr.z, yr.w};
            const float yiv[4] = {yi.x, yi.y, yi.z, yi.w};
            #pragma unroll
            for (int ci = 0; ci < 4; ++ci)
                #pragma unroll
                for (int di = 0; di < 4; ++di){
                    are[ci*4+di] += xrv[ci]*yrv[di] - xiv[ci]*yiv[di];
                    aim[ci*4+di] += xrv[ci]*yiv[di] + xiv[ci]*yrv[di];
                }
        }
    }
    float* gp = Gpart + ((size_t)blockIdx.x * 4 + wave) * 2048;
    #pragma unroll
    for (int ci = 0; ci < 4; ++ci)
        #pragma unroll
        for (int di = 0; di < 4; ++di){
            int idx = ((c0+ci)*32 + d0+di) * 2;
            gp[idx]     = are[ci*4+di];
            gp[idx + 1] = aim[ci*4+di];
        }
}

// ---------- K2b: reduce 128 partials per bh ----------
__global__ __launch_bounds__(256) void k_gram_red(const float* __restrict__ Gpart, float* __restrict__ G){
    int bh = blockIdx.x >> 3;
    int q  = ((blockIdx.x & 7) << 8) + threadIdx.x;
    const float* gp = Gpart + (size_t)bh * 128 * 2048 + q;
    float s = 0.f;
    #pragma unroll 8
    for (int p = 0; p < 128; ++p) s += gp[(size_t)p * 2048];
    G[(size_t)bh * 2048 + q] = s;
}

// ---------- K3: normalize, temperature, complex softmax, fold IF32 * (1/524288) ----------
__global__ __launch_bounds__(256) void k_attn(const float* __restrict__ G, const float* __restrict__ norm2,
                                              const float* __restrict__ temp, float* __restrict__ attn2){
    __shared__ float ar[32*33], ai[32*33];
    int bh = blockIdx.x, h = bh & 7, t = threadIdx.x;
    if (t < 32){
        float tv = temp[h];
        float nc = fmaxf(sqrtf(norm2[(bh<<5) + t]), 1e-12f);
        const float* gr = G + (size_t)bh*2048 + t*64;
        float mr = -1e30f, mi = -1e30f;
        for (int d = 0; d < 32; ++d){
            float nd = fmaxf(sqrtf(norm2[(bh<<5) + d]), 1e-12f);
            float s = tv / (nc * nd);
            float vr = gr[d*2] * s, vi = gr[d*2+1] * s;
            ar[t*33+d] = vr; ai[t*33+d] = vi;
            mr = fmaxf(mr, vr); mi = fmaxf(mi, vi);
        }
        float sr = 0.f, si = 0.f;
        for (int d = 0; d < 32; ++d){
            float er = __expf(ar[t*33+d] - mr), ei = __expf(ai[t*33+d] - mi);
            ar[t*33+d] = er; ai[t*33+d] = ei; sr += er; si += ei;
        }
        sr = 1.f/sr; si = 1.f/si;
        for (int d = 0; d < 32; ++d){ ar[t*33+d] *= sr; ai[t*33+d] *= si; }
    }
    __syncthreads();
    const float S = 1.f / 524288.f;
    for (int q = t; q < 1024; q += 256){
        int e = q >> 5, d = q & 31;
        float sr = 0.f, si = 0.f;
        for (int c = 0; c < 32; ++c){
            float sn, cs; sincos_rev((float)((e*c) & 31) * 0.03125f, sn, cs);
            float xr = ar[c*33+d], xi = ai[c*33+d];
            sr += cs*xr - sn*xi;
            si += cs*xi + sn*xr;
        }
        attn2[(size_t)bh*2048 + q*2]     = sr * S;
        attn2[(size_t)bh*2048 + q*2 + 1] = si * S;
    }
}

// ---------- K4: mix[e][n] = sum_d attn2[e][d] * X[d][n]  (complex) ----------
__global__ __launch_bounds__(256) void k_mix(const float* __restrict__ xre, const float* __restrict__ xim,
                                             const float* __restrict__ attn2,
                                             float* __restrict__ ore, float* __restrict__ oim){
    __shared__ float a2[2048];
    __shared__ float lr[32*65], li[32*65];
    int t = threadIdx.x, lane = t & 63, wave = t >> 6;
    int bh = blockIdx.x >> 5;
    int n0 = (blockIdx.x & 31) << 9;
    size_t cbase = (size_t)bh * 32 * NFFT;
    {
        const float4* s4 = (const float4*)(attn2 + (size_t)bh*2048);
        float4* d4 = (float4*)a2;
        d4[t] = s4[t]; d4[t + 256] = s4[t + 256];
    }
    for (int tile = 0; tile < 8; ++tile){
        int nb = n0 + (tile << 6);
        __syncthreads();
        #pragma unroll
        for (int r = 0; r < 8; ++r){
            int ch = (wave << 3) + r;
            lr[ch*65 + lane] = xre[cbase + (size_t)ch*NFFT + nb + lane];
            li[ch*65 + lane] = xim[cbase + (size_t)ch*NFFT + nb + lane];
        }
        __syncthreads();
        float accr[8] = {0,0,0,0,0,0,0,0}, acci[8] = {0,0,0,0,0,0,0,0};
        for (int d = 0; d < 32; d += 2){
            float xr0 = lr[d*65 + lane],     xi0 = li[d*65 + lane];
            float xr1 = lr[(d+1)*65 + lane], xi1 = li[(d+1)*65 + lane];
            #pragma unroll
            for (int k = 0; k < 8; ++k){
                int e = (wave << 3) + k;
                const float4 w = *(const float4*)&a2[(e << 6) + (d << 1)];
                accr[k] += w.x*xr0 - w.y*xi0 + w.z*xr1 - w.w*xi1;
                acci[k] += w.x*xi0 + w.y*xr0 + w.z*xi1 + w.w*xr1;
            }
        }
        #pragma unroll
        for (int k = 0; k < 8; ++k){
            int e = (wave << 3) + k;
            ore[cbase + (size_t)e*NFFT + nb + lane] = accr[k];
            oim[cbase + (size_t)e*NFFT + nb + lane] = acci[k];
        }
    }
}

// ---------- K5: fused 16384-pt inverse FFT + abs per row, 1024 threads; PACKED bf16(hi|lo) into io ----------
__global__ __launch_bounds__(1024) void k_ifft_n(const float* ire, float* io){
    __shared__ float sr[128*129], si[128*129];
    int lane = threadIdx.x & 63, wave = threadIdx.x >> 6;
    size_t rb = (size_t)blockIdx.x * NFFT;
    TwI tw; make_twi(tw);
    #pragma unroll 2
    for (int it = 0; it < 8; ++it){
        int jw = (wave << 3) + it;
        size_t base = rb + ((size_t)jw << 7);
        float a0 = ire[base + lane], b0 = io[base + lane];
        float a1 = ire[base + lane + 64], b1 = io[base + lane + 64];
        dit128t(tw, a0, b0, a1, b1);
        int kw = rev7(jw);
        float sn, cs;
        sincos_rev((float)(lane * kw) * 6.103515625e-05f, sn, cs);
        float r = a0*cs - b0*sn, i2 = a0*sn + b0*cs;
        sr[lane*129 + jw] = r; si[lane*129 + jw] = i2;
        sincos_rev((float)((lane + 64) * kw) * 6.103515625e-05f, sn, cs);
        r = a1*cs - b1*sn; i2 = a1*sn + b1*cs;
        sr[(lane+64)*129 + jw] = r; si[(lane+64)*129 + jw] = i2;
    }
    __syncthreads();
    float av[8][2];
    #pragma unroll 2
    for (int it = 0; it < 8; ++it){
        int pw = (wave << 3) + it;
        float a0 = sr[pw*129 + lane],      b0 = si[pw*129 + lane];
        float a1 = sr[pw*129 + lane + 64], b1 = si[pw*129 + lane + 64];
        dit128t(tw, a0, b0, a1, b1);
        av[it][0] = __uint_as_float(packsplit(sqrtf(a0*a0 + b0*b0)));
        av[it][1] = __uint_as_float(packsplit(sqrtf(a1*a1 + b1*b1)));
    }
    __syncthreads();
    #pragma unroll 2
    for (int it = 0; it < 8; ++it){
        int pw = (wave << 3) + it;
        sr[lane*129 + pw] = av[it][0];
        sr[(lane+64)*129 + pw] = av[it][1];
    }
    __syncthreads();
    int row = threadIdx.x >> 3, cb = (threadIdx.x & 7) << 4;
    size_t ob = rb + ((size_t)row << 7) + cb;
    const float* s = &sr[row*129 + cb];
    #pragma unroll
    for (int q = 0; q < 4; ++q)
        *(float4*)(io + ob + (q << 2)) = make_float4(s[q*4], s[q*4+1], s[q*4+2], s[q*4+3]);
}

// ---------- K6: gating, IN-PLACE, 4-way split for occupancy ----------
__global__ __launch_bounds__(256) void k_gate(float* xre, float* xim,
                                              const float* __restrict__ w1, const float* __restrict__ b1,
                                              const float* __restrict__ bg, const float* __restrict__ bb_,
                                              const float* __restrict__ bm, const float* __restrict__ bv,
                                              const float* __restrict__ w2, const float* __restrict__ b2){
    __shared__ float w1T[256*17];
    __shared__ float w2s[256*16];
    __shared__ float yred[256*17];
    int t = threadIdx.x, g = t >> 6, col = t & 63;
    #pragma unroll
    for (int i = 0; i < 16; ++i) w1T[t*17 + i] = w1[i*256 + t];
    {
        const float4* s4 = (const float4*)w2; float4* d4 = (float4*)w2s;
        #pragma unroll
        for (int i = 0; i < 4; ++i) d4[i*256 + t] = s4[i*256 + t];
    }
    __syncthreads();
    int b = blockIdx.x >> 8;
    int n = ((blockIdx.x & 255) << 6) + col;
    size_t base = ((size_t)b << 8) * NFFT + n;
    float y[16];
    #pragma unroll
    for (int r = 0; r < 16; ++r) y[r] = 0.f;
    for (int c = g << 6; c < (g << 6) + 64; ++c){
        float xr = xre[base + (size_t)c*NFFT];
        #pragma unroll
        for (int r = 0; r < 16; ++r) y[r] += w1T[c*17 + r] * xr;
    }
    #pragma unroll
    for (int r = 0; r < 16; ++r) yred[t*17 + r] = y[r];
    __syncthreads();
    #pragma unroll
    for (int r = 0; r < 16; ++r){
        float v = yred[col*17 + r] + yred[(col+64)*17 + r]
                + yred[(col+128)*17 + r] + yred[(col+192)*17 + r] + b1[r];
        v = (v - bm[r]) * rsqrtf(bv[r] + 1e-5f) * bg[r] + bb_[r];
        y[r] = fmaxf(v, 0.f);
    }
    for (int o = g << 6; o < (g << 6) + 64; ++o){
        float s = b2[o];
        #pragma unroll
        for (int r = 0; r < 16; ++r) s += w2s[o*16 + r] * y[r];
        float gg = 1.f / (1.f + __expf(-s)) * 6.103515625e-05f;   // sigmoid * 1/16384
        float xr = xre[base + (size_t)o*NFFT];
        float xi = xim[base + (size_t)o*NFFT];
        xre[base + (size_t)o*NFFT] = gg * xr;
        xim[base + (size_t)o*NFFT] = gg * xi;
    }
}

// ---------- K7: fused ifft2 per image + abs, 1024 threads -> PACKED bf16(hi|lo) into re plane ----------
__global__ __launch_bounds__(1024) void k_ifft2_gate(float* re_io, const float* im_){
    __shared__ float sr[128*129], si[128*129];
    int lane = threadIdx.x & 63, wave = threadIdx.x >> 6;
    size_t ib = (size_t)blockIdx.x * NFFT;
    TwI tw; make_twi(tw);
    #pragma unroll 2
    for (int it = 0; it < 8; ++it){
        int jw = (wave << 3) + it;
        size_t base = ib + ((size_t)jw << 7);
        float a0 = re_io[base + lane], b0 = im_[base + lane];
        float a1 = re_io[base + lane + 64], b1 = im_[base + lane + 64];
        dit128t(tw, a0, b0, a1, b1);
        sr[lane*129 + jw] = a0;        si[lane*129 + jw] = b0;
        sr[(lane+64)*129 + jw] = a1;   si[(lane+64)*129 + jw] = b1;
    }
    __syncthreads();
    #pragma unroll 2
    for (int it = 0; it < 8; ++it){
        int ph = (wave << 3) + it;
        float a0 = sr[ph*129 + lane],      b0 = si[ph*129 + lane];
        float a1 = sr[ph*129 + lane + 64], b1 = si[ph*129 + lane + 64];
        dit128t(tw, a0, b0, a1, b1);
        size_t o = ib + ((size_t)ph << 7);
        re_io[o + lane]      = __uint_as_float(packsplit(sqrtf(a0*a0 + b0*b0)));
        re_io[o + lane + 64] = __uint_as_float(packsplit(sqrtf(a1*a1 + b1*b1)));
    }
}

// ---------- K7b: pack pw into (hi|lo) u32 ----------
__global__ __launch_bounds__(256) void k_pw_cvt(const float* __restrict__ pw, unsigned* __restrict__ pwp){
    int i = (blockIdx.x << 10) + (threadIdx.x << 2);
    float4 v = *(const float4*)(pw + i);
    uint4 o;
    o.x = packsplit(v.x); o.y = packsplit(v.y); o.z = packsplit(v.z); o.w = packsplit(v.w);
    *(uint4*)(pwp + i) = o;
}

// ---------- K8: projection via bf16 MFMA, pre-packed inputs ----------
union FU { bf16x8 v; unsigned u[4]; };

__global__ __launch_bounds__(256) void k_proj(const unsigned* __restrict__ cat0, const unsigned* __restrict__ cat1,
                                              const unsigned* __restrict__ pwp, float* __restrict__ out){
    __shared__ unsigned As[128*33];   // [o][k] packed, stride 33
    __shared__ unsigned Bs[32*129];   // [k][n] packed, stride 129
    int t = threadIdx.x, lane = t & 63, wave = t >> 6;
    int quad = lane >> 4, l15 = lane & 15;
    int b  = blockIdx.x >> 8;
    int mo = (blockIdx.x >> 7) & 1;
    int nt = blockIdx.x & 127;
    int n0 = nt << 7;
    int wr = (wave >> 1) << 6;
    int wc = (wave & 1) << 6;

    f32x4 acc[4][4];
    #pragma unroll
    for (int i = 0; i < 4; ++i)
        #pragma unroll
        for (int j = 0; j < 4; ++j) acc[i][j] = (f32x4){0.f,0.f,0.f,0.f};

    int ao = t >> 1, ak = (t & 1) << 4;
    int bk = t >> 5, bn = t & 31;

    for (int ks = 0; ks < 16; ++ks){
        int k0 = ks << 5;
        __syncthreads();
        {
            const unsigned* ap = pwp + (size_t)((mo << 7) + ao)*512 + k0 + ak;
            #pragma unroll
            for (int i = 0; i < 16; ++i) As[ao*33 + ak + i] = ap[i];
        }
        {
            #pragma unroll
            for (int p = 0; p < 4; ++p){
                int q = k0 + (p << 3) + bk;
                const unsigned* srow = (q < 256) ? (cat0 + (size_t)((b<<8) + q) * NFFT)
                                                 : (cat1 + (size_t)((b<<8) + (q-256)) * NFFT);
                #pragma unroll
                for (int i = 0; i < 4; ++i){
                    int n = bn + (i << 5);
                    Bs[((p<<3) + bk)*129 + n] = srow[n0 + n];
                }
            }
        }
        __syncthreads();
        FU Ah[4], Al[4], Bh[4], Bl[4];
        #pragma unroll
        for (int mi = 0; mi < 4; ++mi){
            const unsigned* ap = &As[(wr + (mi << 4) + l15)*33 + (quad << 3)];
            #pragma unroll
            for (int p = 0; p < 4; ++p){
                unsigned e0 = ap[2*p], e1 = ap[2*p+1];
                Ah[mi].u[p] = (e0 >> 16) | (e1 & 0xFFFF0000u);
                Al[mi].u[p] = (e0 & 0xFFFFu) | (e1 << 16);
            }
        }
        #pragma unroll
        for (int ni = 0; ni < 4; ++ni){
            int n = wc + (ni << 4) + l15;
            #pragma unroll
            for (int p = 0; p < 4; ++p){
                unsigned e0 = Bs[((quad << 3) + 2*p)*129 + n];
                unsigned e1 = Bs[((quad << 3) + 2*p + 1)*129 + n];
                Bh[ni].u[p] = (e0 >> 16) | (e1 & 0xFFFF0000u);
                Bl[ni].u[p] = (e0 & 0xFFFFu) | (e1 << 16);
            }
        }
        #pragma unroll
        for (int mi = 0; mi < 4; ++mi)
            #pragma unroll
            for (int ni = 0; ni < 4; ++ni){
                acc[mi][ni] = __builtin_amdgcn_mfma_f32_16x16x32_bf16(Ah[mi].v, Bh[ni].v, acc[mi][ni], 0, 0, 0);
                acc[mi][ni] = __builtin_amdgcn_mfma_f32_16x16x32_bf16(Ah[mi].v, Bl[ni].v, acc[mi][ni], 0, 0, 0);
                acc[mi][ni] = __builtin_amdgcn_mfma_f32_16x16x32_bf16(Al[mi].v, Bh[ni].v, acc[mi][ni], 0, 0, 0);
            }
    }
    size_t obase = (size_t)((b << 8) + (mo << 7));
    #pragma unroll
    for (int mi = 0; mi < 4; ++mi)
        #pragma unroll
        for (int ni = 0; ni < 4; ++ni){
            int o_ = wr + (mi << 4) + (quad << 2);
            int n_ = n0 + wc + (ni << 4) + l15;
            float* op = out + (obase + o_)*NFFT + n_;
            #pragma unroll
            for (int r = 0; r < 4; ++r) op[(size_t)r*NFFT] = acc[mi][ni][r];
        }
}

// ---------- host ----------
extern "C" void kernel_launch(void* const* d_in, const int* in_sizes, int n_in,
                              void* d_out, int out_size, void* d_ws, size_t ws_size,
                              hipStream_t stream) {
    const float* x    = (const float*)d_in[0];
    const float* temp = (const float*)d_in[1];
    const float* w1   = (const float*)d_in[2];
    const float* b1   = (const float*)d_in[3];
    const float* bg   = (const float*)d_in[4];
    const float* bb_  = (const float*)d_in[5];
    const float* bm   = (const float*)d_in[6];
    const float* bv   = (const float*)d_in[7];
    const float* w2   = (const float*)d_in[8];
    const float* b2   = (const float*)d_in[9];
    const float* pw   = (const float*)d_in[10];
    float* out = (float*)d_out;

    float* ws = (float*)d_ws;
    float* Are  = ws;            // spectrum re -> gated in-place -> cat1 (packed)
    float* Aim  = ws + NP;       // spectrum im
    float* Ecat = ws + 2*NP;     // Gpart scratch -> mix im -> cat0 (packed, in-place)
    float* norm2 = ws + 3*NP;                  // 1024
    float* G     = norm2 + 1024;               // 65536
    float* attn2 = G + 65536;                  // 65536
    unsigned* pwpack = (unsigned*)(attn2 + 65536);  // 131072
    float* mixre = out;                        // d_out doubles as mix-re scratch
    float* Gpart = Ecat;                       // 8.4M floats, dead until k_mix

    size_t need = (3*NP + 1024 + 65536 + 65536 + 131072) * sizeof(float);
    if (ws_size < need) return;

    k_pw_cvt<<<128, 256, 0, stream>>>(pw, pwpack);
    k_fft2_fwd<<<1024, 1024, 0, stream>>>(x, Are, Aim, norm2);
    k_gram<<<1024, 256, 0, stream>>>(Are, Aim, Gpart);
    k_gram_red<<<256, 256, 0, stream>>>(Gpart, G);
    k_attn<<<32, 256, 0, stream>>>(G, norm2, temp, attn2);
    k_mix<<<1024, 256, 0, stream>>>(Are, Aim, attn2, mixre, Ecat);
    k_ifft_n<<<1024, 1024, 0, stream>>>(mixre, Ecat);
    k_gate<<<1024, 256, 0, stream>>>(Are, Aim, w1, b1, bg, bb_, bm, bv, w2, b2);
    k_ifft2_gate<<<1024, 1024, 0, stream>>>(Are, Aim);
    k_proj<<<1024, 256, 0, stream>>>((const unsigned*)Ecat, (const unsigned*)Are, pwpack, out);
    (void)in_sizes; (void)n_in; (void)out_size; (void)ws_size;
}